// Round 3
// baseline (1349.876 us; speedup 1.0000x reference)
//
#include <hip/hip_runtime.h>
#include <hip/hip_fp16.h>
#include <hip/hip_cooperative_groups.h>

namespace cg = cooperative_groups;

namespace {

typedef _Float16 half8 __attribute__((ext_vector_type(8)));
typedef float f32x4 __attribute__((ext_vector_type(4)));
typedef float f32x4v __attribute__((ext_vector_type(4)));

constexpr int kN = 65536;
constexpr int kD = 32;
constexpr int kPts = 2 * kN;                 // 131072 points (B*N)
constexpr int kThreads = 256;                // 4 waves
constexpr int kPtsPerBlk = 64;               // fallback: 16 points per wave
constexpr int kBlocks = kPts / kPtsPerBlk;   // fallback grid: 2048
constexpr int kCoopBlocks = 1024;            // fused grid: 4 blocks/CU co-resident
constexpr int kPtsPerCoop = 128;             // points per fused block (2 chunks of 64)
constexpr int kNumFrags = 24;
static_assert(kCoopBlocks * kPtsPerCoop == kPts, "coop grid must tile points");
static_assert(kN % kPtsPerCoop == 0, "blocks must not straddle batch boundary");

__device__ __forceinline__ float relu_(float v) { return fmaxf(v, 0.f); }
__device__ __forceinline__ float lrelu_(float v) { return v >= 0.f ? v : 0.2f * v; }

// channel permutation induced by the interleaved z-row layout.
__device__ __forceinline__ int pi_(int k) {
    const int c = ((k >> 3) << 2) + ((k & 7) >> 1);
    return (k & 1) ? c + 16 : c;
}

// fallback swizzle (2048 blocks x 64 pts)
__device__ __forceinline__ int swizzled_pbase(int bid) {
    const int xcd   = bid & 7;
    const int slot  = bid >> 3;
    const int batch = xcd >> 2;
    const int local = (xcd & 3) * (kBlocks / 8) + slot;
    return batch * kN + local * kPtsPerBlk;
}

// fused swizzle (1024 blocks x 128 pts): XCDs 0-3 -> batch 0, 4-7 -> batch 1
__device__ __forceinline__ int coop_pbase(int bid) {
    const int xcd   = bid & 7;
    const int slot  = bid >> 3;                    // 0..127
    const int batch = xcd >> 2;
    const int local = (xcd & 3) * 128 + slot;      // 0..511
    return batch * kN + local * kPtsPerCoop;
}

__device__ __forceinline__ void build_wpack(int tid, const float* __restrict__ W2d,
                                            const float* __restrict__ W1d,
                                            uint4* __restrict__ wpack)
{
    for (int id = tid; id < kNumFrags * 64; id += kThreads) {
        const int fid = id >> 6, l = id & 63, n = l & 15, q = l >> 4;
        half8 v;
        if (fid < 2) {
            const int h = fid;
#pragma unroll
            for (int j = 0; j < 8; ++j)
                v[j] = (_Float16)W2d[(q * 8 + j) * kD + h * 16 + n];
        } else {
            const int rel = fid - 2;
            const int layer = (rel < 18) ? rel / 6 : 3;
            const int sub   = (rel < 18) ? rel % 6 : rel - 18;
            if (sub < 4) {
                const int p = sub >> 1, h = sub & 1;
#pragma unroll
                for (int j = 0; j < 8; ++j)
                    v[j] = (_Float16)W1d[layer * 2048 + (p * 32 + pi_(q * 8 + j)) * kD + h * 16 + n];
            } else {
                const int h = sub - 4;
#pragma unroll
                for (int j = 0; j < 8; ++j)
                    v[j] = (_Float16)W2d[(layer + 1) * 1024 + pi_(q * 8 + j) * kD + h * 16 + n];
            }
        }
        wpack[id] = *reinterpret_cast<const uint4*>(&v);
    }
}

// ---------------------------------------------------------------------------
// One layer x one 64-point chunk of the fused kernel. Numerically identical
// to the verified blk_kernel path: gather -> packed fp16 max/mean -> LDS
// bounce -> conv2 MFMA -> fp32 transpose -> epilogue (sacc in LDS, prev in
// regs) -> z-next MFMA. LAYER: 0=first, 1/2=mid, 3=last (writes out).
// ---------------------------------------------------------------------------
template <int LAYER>
__device__ __forceinline__ void layer_chunk(
    const int pbase, const int lpbase, const int lane, const int n, const int q,
    const int base,
    const uint4* __restrict__ zsrc, __half2* __restrict__ znext,
    const uint4* __restrict__ sidx,                    // LDS: packed u16 idx
    const uint4* __restrict__ wf,
    const float* __restrict__ g1v, const float* __restrict__ b1v,
    const float* __restrict__ g2v, const float* __restrict__ b2v,
    float* __restrict__ out,
    f32x4* __restrict__ sacc2,                         // LDS: this thread {s0,s1}
    half8& prevh,
    _Float16 (* __restrict__ gmaxw)[40], _Float16 (* __restrict__ gmeanw)[40],
    float2 (* __restrict__ tbw)[17])
{
    const int point = pbase + n;
    const int gpt = lane >> 2;
    const int gq  = lane & 3;
    const int lgp = lpbase + gpt;
    const uint4 iv0 = sidx[lgp * 2 + 0];
    const uint4 iv1 = sidx[lgp * 2 + 1];

    // phase 1: issue ALL 16 gather loads
    uint4 gbuf[16];
#pragma unroll
    for (int k = 0; k < 16; ++k) {
        unsigned word;
        if (k < 8) word = reinterpret_cast<const unsigned*>(&iv0)[k >> 1];
        else       word = reinterpret_cast<const unsigned*>(&iv1)[(k - 8) >> 1];
        const int row = (k & 1) ? (int)(word >> 16) : (int)(word & 0xFFFFu);
        gbuf[k] = zsrc[(base + row) * 4 + gq];
    }
    // phase 2: packed fp16 reduce
    half8 hmx = (half8)(_Float16)0;
    half8 hsm = (half8)(_Float16)0;
#pragma unroll
    for (int k = 0; k < 16; ++k) {
        const half8 hv = *reinterpret_cast<const half8*>(&gbuf[k]);
        hsm += hv;
#pragma unroll
        for (int c = 0; c < 8; ++c)
            hmx[c] = hmx[c] > hv[c] ? hmx[c] : hv[c];
    }
    {
        const half8 hmn = hsm * (_Float16)0.0625;
        *reinterpret_cast<uint4*>(&gmaxw[gpt][gq * 8]) =
            *reinterpret_cast<const uint4*>(&hmx);
        *reinterpret_cast<uint4*>(&gmeanw[gpt][gq * 8]) =
            *reinterpret_cast<const uint4*>(&hmn);
    }
    __builtin_amdgcn_wave_barrier();

    const half8 amax  = *reinterpret_cast<const half8*>(&gmaxw[n][q * 8]);
    const half8 amean = *reinterpret_cast<const half8*>(&gmeanw[n][q * 8]);

    const uint4 f0 = wf[0 * 64 + lane];
    const uint4 f1 = wf[1 * 64 + lane];
    const uint4 f2 = wf[2 * 64 + lane];
    const uint4 f3 = wf[3 * 64 + lane];
    const half8 bA0 = *reinterpret_cast<const half8*>(&f0);
    const half8 bA1 = *reinterpret_cast<const half8*>(&f1);
    const half8 bB0 = *reinterpret_cast<const half8*>(&f2);
    const half8 bB1 = *reinterpret_cast<const half8*>(&f3);

    f32x4 acc0 = {0.f, 0.f, 0.f, 0.f}, acc1 = {0.f, 0.f, 0.f, 0.f};
    acc0 = __builtin_amdgcn_mfma_f32_16x16x32_f16(amax,  bA0, acc0, 0, 0, 0);
    acc0 = __builtin_amdgcn_mfma_f32_16x16x32_f16(amean, bB0, acc0, 0, 0, 0);
    acc1 = __builtin_amdgcn_mfma_f32_16x16x32_f16(amax,  bA1, acc1, 0, 0, 0);
    acc1 = __builtin_amdgcn_mfma_f32_16x16x32_f16(amean, bB1, acc1, 0, 0, 0);

    const float g10 = g1v[n], g11 = g1v[16 + n];
    const float c10 = b1v[n], c11 = b1v[16 + n];
#pragma unroll
    for (int r = 0; r < 4; ++r) {
        tbw[q * 4 + r][n] = make_float2(fmaf(acc0[r], g10, c10),
                                        fmaf(acc1[r], g11, c11));
    }
    __builtin_amdgcn_wave_barrier();
    float y8[8];
#pragma unroll
    for (int s = 0; s < 4; ++s) {
        const float2 f = tbw[n][q * 4 + s];
        y8[2 * s] = f.x; y8[2 * s + 1] = f.y;
    }

    // ---- epilogue: sacc in LDS, prev in registers ----
    float t8[8];
    if constexpr (LAYER == 0) {
        sacc2[0] = (f32x4){y8[0], y8[2], y8[4], y8[6]};
        sacc2[1] = (f32x4){y8[1], y8[3], y8[5], y8[7]};
#pragma unroll
        for (int c = 0; c < 8; ++c) prevh[c] = (_Float16)y8[c];
#pragma unroll
        for (int c = 0; c < 8; ++c) t8[c] = lrelu_(y8[c]);
    } else if constexpr (LAYER == 1 || LAYER == 2) {
        f32x4 s0 = sacc2[0], s1 = sacc2[1];
        s0.x += y8[0]; s0.y += y8[2]; s0.z += y8[4]; s0.w += y8[6];
        s1.x += y8[1]; s1.y += y8[3]; s1.z += y8[5]; s1.w += y8[7];
        sacc2[0] = s0; sacc2[1] = s1;
#pragma unroll
        for (int c = 0; c < 8; ++c)
            t8[c] = lrelu_(y8[c] + (float)prevh[c]);
#pragma unroll
        for (int c = 0; c < 8; ++c) prevh[c] = (_Float16)y8[c];
    } else {  // LAYER == 3: out = lrelu(sacc + y); nontemporal (zero reuse)
        const f32x4 s0 = sacc2[0], s1 = sacc2[1];
        const int sb0 = point * kD + q * 4;
        const int sb1 = sb0 + 16;
        __builtin_nontemporal_store(
            (f32x4v){lrelu_(s0.x + y8[0]), lrelu_(s0.y + y8[2]),
                     lrelu_(s0.z + y8[4]), lrelu_(s0.w + y8[6])},
            reinterpret_cast<f32x4v*>(out) + (sb0 >> 2));
        __builtin_nontemporal_store(
            (f32x4v){lrelu_(s1.x + y8[1]), lrelu_(s1.y + y8[3]),
                     lrelu_(s1.z + y8[5]), lrelu_(s1.w + y8[7])},
            reinterpret_cast<f32x4v*>(out) + (sb1 >> 2));
        return;
    }

    // ---- z-next MFMA; C-layout-native store (stays cached: reused next layer)
    half8 at;
#pragma unroll
    for (int c = 0; c < 8; ++c) at[c] = (_Float16)t8[c];
    const uint4 f4 = wf[4 * 64 + lane];
    const uint4 f5 = wf[5 * 64 + lane];
    const half8 bz0 = *reinterpret_cast<const half8*>(&f4);
    const half8 bz1 = *reinterpret_cast<const half8*>(&f5);
    f32x4 az0 = {0.f, 0.f, 0.f, 0.f}, az1 = {0.f, 0.f, 0.f, 0.f};
    az0 = __builtin_amdgcn_mfma_f32_16x16x32_f16(at, bz0, az0, 0, 0, 0);
    az1 = __builtin_amdgcn_mfma_f32_16x16x32_f16(at, bz1, az1, 0, 0, 0);

    const float g20 = g2v[n], g21 = g2v[16 + n];
    const float c20 = b2v[n], c21 = b2v[16 + n];
#pragma unroll
    for (int r = 0; r < 4; ++r) {
        const int pm = pbase + q * 4 + r;
        znext[pm * 16 + n] = __floats2half2_rn(relu_(fmaf(az0[r], g20, c20)),
                                               relu_(fmaf(az1[r], g21, c21)));
    }
}

// ---------------------------------------------------------------------------
// Fused cooperative kernel: zprep + 4 blk layers with grid syncs between.
// Eliminates sacc/prev/cur global round-trips (regs/LDS) and idx16 global
// traffic (block-local LDS); L2 is left to the z gather map.
// ---------------------------------------------------------------------------
__global__ __launch_bounds__(kThreads, 4)
void fused_kernel(const float* __restrict__ x, const int4* __restrict__ idx4,
                  const float* __restrict__ W2d, const float* __restrict__ W1d,
                  const float* __restrict__ g1a, const float* __restrict__ b1a,
                  const float* __restrict__ g2a, const float* __restrict__ b2a,
                  __half2* __restrict__ zA, __half2* __restrict__ zB,
                  uint4* __restrict__ wpack, float* __restrict__ out)
{
    __shared__ __align__(16) _Float16 gmax[4][16][40];      // 5120 B
    __shared__ __align__(16) _Float16 gmean[4][16][40];     // 5120 B
    __shared__ float2 tb[4][16][17];                        // 8704 B
    __shared__ uint4 sidx[kPtsPerCoop * 2];                 // 4096 B
    __shared__ f32x4 saccs[2][kThreads][2];                 // 16384 B -> 39.4 KB total

    const int tid  = threadIdx.x;
    const int w    = tid >> 6;
    const int lane = tid & 63;
    const int n    = lane & 15;
    const int q    = lane >> 4;
    const int blockPbase = coop_pbase(blockIdx.x);
    const int base = blockPbase & ~(kN - 1);

    cg::grid_group grid = cg::this_grid();

    // ---- phase 0: wpack (block 0 only) ----
    if (blockIdx.x == 0) build_wpack(tid, W2d, W1d, wpack);

    // ---- phase 0: pack idx -> LDS (thread t: local point t>>1, half t&1) ----
    {
        const int lp = tid >> 1, h = tid & 1;
        const int p  = blockPbase + lp;
        const int4 a = idx4[p * 4 + 2 * h];
        const int4 b = idx4[p * 4 + 2 * h + 1];
        uint4 o;
        o.x = (unsigned)(a.x & 0xFFFF) | ((unsigned)a.y << 16);
        o.y = (unsigned)(a.z & 0xFFFF) | ((unsigned)a.w << 16);
        o.z = (unsigned)(b.x & 0xFFFF) | ((unsigned)b.y << 16);
        o.w = (unsigned)(b.z & 0xFFFF) | ((unsigned)b.w << 16);
        sidx[lp * 2 + h] = o;
    }

    // ---- phase 0: z1 = relu((x @ W2_0) * g2_0 + b2_0) for both chunks ----
    {
        half8 b0, b1;
#pragma unroll
        for (int j = 0; j < 8; ++j) {
            b0[j] = (_Float16)W2d[(q * 8 + j) * kD + n];
            b1[j] = (_Float16)W2d[(q * 8 + j) * kD + 16 + n];
        }
        const float g20 = g2a[n], g21 = g2a[16 + n];
        const float c20 = b2a[n], c21 = b2a[16 + n];
#pragma unroll
        for (int c = 0; c < 2; ++c) {
            const int pbase = blockPbase + c * 64 + w * 16;
            const int point = pbase + n;
            const float4 x0 = reinterpret_cast<const float4*>(x)[point * 8 + q * 2];
            const float4 x1 = reinterpret_cast<const float4*>(x)[point * 8 + q * 2 + 1];
            half8 ax;
            ax[0] = (_Float16)x0.x; ax[1] = (_Float16)x0.y;
            ax[2] = (_Float16)x0.z; ax[3] = (_Float16)x0.w;
            ax[4] = (_Float16)x1.x; ax[5] = (_Float16)x1.y;
            ax[6] = (_Float16)x1.z; ax[7] = (_Float16)x1.w;
            f32x4 a0 = {0.f, 0.f, 0.f, 0.f}, a1 = {0.f, 0.f, 0.f, 0.f};
            a0 = __builtin_amdgcn_mfma_f32_16x16x32_f16(ax, b0, a0, 0, 0, 0);
            a1 = __builtin_amdgcn_mfma_f32_16x16x32_f16(ax, b1, a1, 0, 0, 0);
#pragma unroll
            for (int r = 0; r < 4; ++r) {
                const int pm = pbase + q * 4 + r;
                zA[pm * 16 + n] = __floats2half2_rn(relu_(fmaf(a0[r], g20, c20)),
                                                    relu_(fmaf(a1[r], g21, c21)));
            }
        }
    }

    __threadfence();
    grid.sync();
    __threadfence();

    const int pb0 = blockPbase + w * 16;
    const int pb1 = blockPbase + 64 + w * 16;
    const int lp0 = w * 16;
    const int lp1 = 64 + w * 16;
    half8 phA, phB;

    // ---- layer 0: zA -> zB ----
    layer_chunk<0>(pb0, lp0, lane, n, q, base, (const uint4*)zA, zB, sidx,
                   wpack + (2 + 0 * 6) * 64, g1a, b1a, g2a + 1 * kD, b2a + 1 * kD,
                   out, &saccs[0][tid][0], phA, gmax[w], gmean[w], tb[w]);
    layer_chunk<0>(pb1, lp1, lane, n, q, base, (const uint4*)zA, zB, sidx,
                   wpack + (2 + 0 * 6) * 64, g1a, b1a, g2a + 1 * kD, b2a + 1 * kD,
                   out, &saccs[1][tid][0], phB, gmax[w], gmean[w], tb[w]);
    __threadfence();
    grid.sync();
    __threadfence();

    // ---- layer 1: zB -> zA ----
    layer_chunk<1>(pb0, lp0, lane, n, q, base, (const uint4*)zB, zA, sidx,
                   wpack + (2 + 1 * 6) * 64, g1a + 1 * kD, b1a + 1 * kD,
                   g2a + 2 * kD, b2a + 2 * kD,
                   out, &saccs[0][tid][0], phA, gmax[w], gmean[w], tb[w]);
    layer_chunk<1>(pb1, lp1, lane, n, q, base, (const uint4*)zB, zA, sidx,
                   wpack + (2 + 1 * 6) * 64, g1a + 1 * kD, b1a + 1 * kD,
                   g2a + 2 * kD, b2a + 2 * kD,
                   out, &saccs[1][tid][0], phB, gmax[w], gmean[w], tb[w]);
    __threadfence();
    grid.sync();
    __threadfence();

    // ---- layer 2: zA -> zB (both chunks gather from zA) ----
    layer_chunk<2>(pb0, lp0, lane, n, q, base, (const uint4*)zA, zB, sidx,
                   wpack + (2 + 2 * 6) * 64, g1a + 2 * kD, b1a + 2 * kD,
                   g2a + 3 * kD, b2a + 3 * kD,
                   out, &saccs[0][tid][0], phA, gmax[w], gmean[w], tb[w]);
    layer_chunk<2>(pb1, lp1, lane, n, q, base, (const uint4*)zA, zB, sidx,
                   wpack + (2 + 2 * 6) * 64, g1a + 2 * kD, b1a + 2 * kD,
                   g2a + 3 * kD, b2a + 3 * kD,
                   out, &saccs[1][tid][0], phB, gmax[w], gmean[w], tb[w]);
    __threadfence();
    grid.sync();
    __threadfence();

    // ---- layer 3: zB -> out ----
    layer_chunk<3>(pb0, lp0, lane, n, q, base, (const uint4*)zB, nullptr, sidx,
                   wpack + (2 + 3 * 6) * 64, g1a + 3 * kD, b1a + 3 * kD,
                   nullptr, nullptr,
                   out, &saccs[0][tid][0], phA, gmax[w], gmean[w], tb[w]);
    layer_chunk<3>(pb1, lp1, lane, n, q, base, (const uint4*)zB, nullptr, sidx,
                   wpack + (2 + 3 * 6) * 64, g1a + 3 * kD, b1a + 3 * kD,
                   nullptr, nullptr,
                   out, &saccs[1][tid][0], phB, gmax[w], gmean[w], tb[w]);
}

// ---------------------------------------------------------------------------
// Fallback path: verified 5-dispatch pipeline (171.8 us baseline, no nt).
// ---------------------------------------------------------------------------
__global__ __launch_bounds__(kThreads, 4)
void zprep_kernel(const float* __restrict__ x, const int4* __restrict__ idx4,
                  const float* __restrict__ W2d, const float* __restrict__ W1d,
                  const float* __restrict__ g2v, const float* __restrict__ b2v,
                  __half2* __restrict__ z, uint2* __restrict__ idx16,
                  uint4* __restrict__ wpack)
{
    const int tid = threadIdx.x;
    if (blockIdx.x == 0) build_wpack(tid, W2d, W1d, wpack);
    {
        const int p = blockIdx.x * kPtsPerBlk + (tid >> 2);
        const int part = tid & 3;
        const int4 iv = idx4[p * 4 + part];
        uint2 o;
        o.x = (unsigned)(iv.x & 0xFFFF) | ((unsigned)iv.y << 16);
        o.y = (unsigned)(iv.z & 0xFFFF) | ((unsigned)iv.w << 16);
        idx16[p * 4 + part] = o;
    }
    const int w    = tid >> 6;
    const int lane = tid & 63;
    const int n    = lane & 15;
    const int q    = lane >> 4;
    const int pbase = blockIdx.x * kPtsPerBlk + w * 16;
    const int point = pbase + n;

    const float4 x0 = reinterpret_cast<const float4*>(x)[point * 8 + q * 2];
    const float4 x1 = reinterpret_cast<const float4*>(x)[point * 8 + q * 2 + 1];
    half8 ax;
    ax[0] = (_Float16)x0.x; ax[1] = (_Float16)x0.y;
    ax[2] = (_Float16)x0.z; ax[3] = (_Float16)x0.w;
    ax[4] = (_Float16)x1.x; ax[5] = (_Float16)x1.y;
    ax[6] = (_Float16)x1.z; ax[7] = (_Float16)x1.w;

    half8 b0, b1;
#pragma unroll
    for (int j = 0; j < 8; ++j) {
        b0[j] = (_Float16)W2d[(q * 8 + j) * kD + n];
        b1[j] = (_Float16)W2d[(q * 8 + j) * kD + 16 + n];
    }
    f32x4 a0 = {0.f, 0.f, 0.f, 0.f}, a1 = {0.f, 0.f, 0.f, 0.f};
    a0 = __builtin_amdgcn_mfma_f32_16x16x32_f16(ax, b0, a0, 0, 0, 0);
    a1 = __builtin_amdgcn_mfma_f32_16x16x32_f16(ax, b1, a1, 0, 0, 0);

    const float g20 = g2v[n], g21 = g2v[16 + n];
    const float c20 = b2v[n], c21 = b2v[16 + n];
#pragma unroll
    for (int r = 0; r < 4; ++r) {
        const int pm = pbase + q * 4 + r;
        z[pm * 16 + n] = __floats2half2_rn(relu_(fmaf(a0[r], g20, c20)),
                                           relu_(fmaf(a1[r], g21, c21)));
    }
}

template <int MODE>
__global__ __launch_bounds__(kThreads, 4)
void blk_kernel(const uint4* __restrict__ zsrc, const uint4* __restrict__ idx16,
                const uint4* __restrict__ wfrag,
                const float* __restrict__ g1v, const float* __restrict__ b1v,
                const float* __restrict__ g2v, const float* __restrict__ b2v,
                const uint4* __restrict__ prev, uint4* __restrict__ cur,
                float* __restrict__ sacc, __half2* __restrict__ znext)
{
    __shared__ __align__(16) _Float16 gmax[4][16][40];
    __shared__ __align__(16) _Float16 gmean[4][16][40];
    __shared__ float2 tb[4][16][17];

    const int tid  = threadIdx.x;
    const int w    = tid >> 6;
    const int lane = tid & 63;
    const int n    = lane & 15;
    const int q    = lane >> 4;
    const int blockPbase = swizzled_pbase(blockIdx.x);
    const int pbase = blockPbase + w * 16;
    const int point = pbase + n;
    const int base  = pbase & ~(kN - 1);

    const int sb0 = point * kD + q * 4;
    const int sb1 = sb0 + 16;
    float4 sv0, sv1; uint4 pv;
    if (MODE != 0) {
        sv0 = reinterpret_cast<const float4*>(sacc)[sb0 >> 2];
        sv1 = reinterpret_cast<const float4*>(sacc)[sb1 >> 2];
    }
    if (MODE == 1 || MODE == 2) pv = prev[point * 4 + q];

    const int gpt = lane >> 2;
    const int gq  = lane & 3;
    const int gpoint = pbase + gpt;
    const uint4 iv0 = idx16[gpoint * 2 + 0];
    const uint4 iv1 = idx16[gpoint * 2 + 1];

    uint4 gbuf[16];
#pragma unroll
    for (int k = 0; k < 16; ++k) {
        unsigned word;
        if (k < 8) word = reinterpret_cast<const unsigned*>(&iv0)[k >> 1];
        else       word = reinterpret_cast<const unsigned*>(&iv1)[(k - 8) >> 1];
        const int row = (k & 1) ? (int)(word >> 16) : (int)(word & 0xFFFFu);
        gbuf[k] = zsrc[(base + row) * 4 + gq];
    }
    half8 hmx = (half8)(_Float16)0;
    half8 hsm = (half8)(_Float16)0;
#pragma unroll
    for (int k = 0; k < 16; ++k) {
        const half8 hv = *reinterpret_cast<const half8*>(&gbuf[k]);
        hsm += hv;
#pragma unroll
        for (int c = 0; c < 8; ++c)
            hmx[c] = hmx[c] > hv[c] ? hmx[c] : hv[c];
    }
    {
        const half8 hmn = hsm * (_Float16)0.0625;
        *reinterpret_cast<uint4*>(&gmax[w][gpt][gq * 8]) =
            *reinterpret_cast<const uint4*>(&hmx);
        *reinterpret_cast<uint4*>(&gmean[w][gpt][gq * 8]) =
            *reinterpret_cast<const uint4*>(&hmn);
    }
    __builtin_amdgcn_wave_barrier();

    const half8 amax  = *reinterpret_cast<const half8*>(&gmax[w][n][q * 8]);
    const half8 amean = *reinterpret_cast<const half8*>(&gmean[w][n][q * 8]);

    const uint4 f0 = wfrag[0 * 64 + lane];
    const uint4 f1 = wfrag[1 * 64 + lane];
    const uint4 f2 = wfrag[2 * 64 + lane];
    const uint4 f3 = wfrag[3 * 64 + lane];
    const half8 bA0 = *reinterpret_cast<const half8*>(&f0);
    const half8 bA1 = *reinterpret_cast<const half8*>(&f1);
    const half8 bB0 = *reinterpret_cast<const half8*>(&f2);
    const half8 bB1 = *reinterpret_cast<const half8*>(&f3);

    f32x4 acc0 = {0.f, 0.f, 0.f, 0.f}, acc1 = {0.f, 0.f, 0.f, 0.f};
    acc0 = __builtin_amdgcn_mfma_f32_16x16x32_f16(amax,  bA0, acc0, 0, 0, 0);
    acc0 = __builtin_amdgcn_mfma_f32_16x16x32_f16(amean, bB0, acc0, 0, 0, 0);
    acc1 = __builtin_amdgcn_mfma_f32_16x16x32_f16(amax,  bA1, acc1, 0, 0, 0);
    acc1 = __builtin_amdgcn_mfma_f32_16x16x32_f16(amean, bB1, acc1, 0, 0, 0);

    const float g10 = g1v[n], g11 = g1v[16 + n];
    const float c10 = b1v[n], c11 = b1v[16 + n];
#pragma unroll
    for (int r = 0; r < 4; ++r) {
        tb[w][q * 4 + r][n] = make_float2(fmaf(acc0[r], g10, c10),
                                          fmaf(acc1[r], g11, c11));
    }
    __builtin_amdgcn_wave_barrier();
    float y8[8];
#pragma unroll
    for (int s = 0; s < 4; ++s) {
        const float2 f = tb[w][n][q * 4 + s];
        y8[2 * s] = f.x; y8[2 * s + 1] = f.y;
    }

    float t8[8];
    if (MODE == 0) {
        reinterpret_cast<float4*>(sacc)[sb0 >> 2] = make_float4(y8[0], y8[2], y8[4], y8[6]);
        reinterpret_cast<float4*>(sacc)[sb1 >> 2] = make_float4(y8[1], y8[3], y8[5], y8[7]);
        half8 ch;
#pragma unroll
        for (int c = 0; c < 8; ++c) ch[c] = (_Float16)y8[c];
        cur[point * 4 + q] = *reinterpret_cast<const uint4*>(&ch);
#pragma unroll
        for (int c = 0; c < 8; ++c) t8[c] = lrelu_(y8[c]);
    } else if (MODE == 1 || MODE == 2) {
        sv0.x += y8[0]; sv0.y += y8[2]; sv0.z += y8[4]; sv0.w += y8[6];
        sv1.x += y8[1]; sv1.y += y8[3]; sv1.z += y8[5]; sv1.w += y8[7];
        reinterpret_cast<float4*>(sacc)[sb0 >> 2] = sv0;
        reinterpret_cast<float4*>(sacc)[sb1 >> 2] = sv1;
        const __half2* ph = reinterpret_cast<const __half2*>(&pv);
#pragma unroll
        for (int c = 0; c < 4; ++c) {
            const float2 f = __half22float2(ph[c]);
            t8[2 * c]     = lrelu_(y8[2 * c] + f.x);
            t8[2 * c + 1] = lrelu_(y8[2 * c + 1] + f.y);
        }
        if (MODE == 1) {
            half8 ch;
#pragma unroll
            for (int c = 0; c < 8; ++c) ch[c] = (_Float16)y8[c];
            cur[point * 4 + q] = *reinterpret_cast<const uint4*>(&ch);
        }
    } else {
        reinterpret_cast<float4*>(sacc)[sb0 >> 2] =
            make_float4(lrelu_(sv0.x + y8[0]), lrelu_(sv0.y + y8[2]),
                        lrelu_(sv0.z + y8[4]), lrelu_(sv0.w + y8[6]));
        reinterpret_cast<float4*>(sacc)[sb1 >> 2] =
            make_float4(lrelu_(sv1.x + y8[1]), lrelu_(sv1.y + y8[3]),
                        lrelu_(sv1.z + y8[5]), lrelu_(sv1.w + y8[7]));
        return;
    }

    half8 at;
#pragma unroll
    for (int c = 0; c < 8; ++c) at[c] = (_Float16)t8[c];
    const uint4 f4 = wfrag[4 * 64 + lane];
    const uint4 f5 = wfrag[5 * 64 + lane];
    const half8 bz0 = *reinterpret_cast<const half8*>(&f4);
    const half8 bz1 = *reinterpret_cast<const half8*>(&f5);
    f32x4 az0 = {0.f, 0.f, 0.f, 0.f}, az1 = {0.f, 0.f, 0.f, 0.f};
    az0 = __builtin_amdgcn_mfma_f32_16x16x32_f16(at, bz0, az0, 0, 0, 0);
    az1 = __builtin_amdgcn_mfma_f32_16x16x32_f16(at, bz1, az1, 0, 0, 0);

    const float g20 = g2v[n], g21 = g2v[16 + n];
    const float c20 = b2v[n], c21 = b2v[16 + n];
#pragma unroll
    for (int r = 0; r < 4; ++r) {
        const int pm = pbase + q * 4 + r;
        znext[pm * 16 + n] = __floats2half2_rn(relu_(fmaf(az0[r], g20, c20)),
                                               relu_(fmaf(az1[r], g21, c21)));
    }
}

}  // namespace

extern "C" void kernel_launch(void* const* d_in, const int* in_sizes, int n_in,
                              void* d_out, int out_size, void* d_ws, size_t ws_size,
                              hipStream_t stream)
{
    const float* x   = (const float*)d_in[0];
    const int4*  idx = (const int4*)d_in[1];
    const float* W2d = (const float*)d_in[2];
    const float* g2  = (const float*)d_in[3];
    const float* b2  = (const float*)d_in[4];
    const float* W1d = (const float*)d_in[5];
    const float* g1  = (const float*)d_in[6];
    const float* b1  = (const float*)d_in[7];
    float* out = (float*)d_out;
    char*  ws  = (char*)d_ws;

    constexpr size_t kHalfMap = (size_t)kPts * kD * sizeof(__half);  // 8 MB
    __half2* zA = (__half2*)(ws);
    __half2* zB = (__half2*)(ws + kHalfMap);
    uint4*   cA = (uint4*)(ws + 2 * kHalfMap);
    uint4*   cB = (uint4*)(ws + 3 * kHalfMap);
    uint2*   idx16 = (uint2*)(ws + 4 * kHalfMap);
    uint4*   wpack = (uint4*)(ws + 4 * kHalfMap + (size_t)kPts * 32);

    // ---- fused cooperative path ----
    {
        const float* g1a = g1; const float* b1a = b1;
        const float* g2a = g2; const float* b2a = b2;
        __half2* zAp = zA; __half2* zBp = zB;
        uint4* wpackp = wpack; float* outp = out;
        void* args[] = {(void*)&x, (void*)&idx, (void*)&W2d, (void*)&W1d,
                        (void*)&g1a, (void*)&b1a, (void*)&g2a, (void*)&b2a,
                        (void*)&zAp, (void*)&zBp, (void*)&wpackp, (void*)&outp};
        hipError_t err = hipLaunchCooperativeKernel(
            (const void*)fused_kernel, dim3(kCoopBlocks), dim3(kThreads),
            args, 0, stream);
        if (err == hipSuccess) return;
        (void)hipGetLastError();   // clear sticky error; fall back
    }

    // ---- fallback: verified 5-dispatch pipeline ----
    const dim3 grid(kBlocks), blk(kThreads);
    zprep_kernel<<<grid, blk, 0, stream>>>(x, idx, W2d, W1d, g2, b2,
                                           zA, idx16, wpack);
    const uint4* i16 = (const uint4*)idx16;
    blk_kernel<0><<<grid, blk, 0, stream>>>((const uint4*)zA, i16,
        wpack + (2 + 0 * 6) * 64, g1, b1, g2 + 1 * kD, b2 + 1 * kD,
        nullptr, cA, out, zB);
    blk_kernel<1><<<grid, blk, 0, stream>>>((const uint4*)zB, i16,
        wpack + (2 + 1 * 6) * 64, g1 + 1 * kD, b1 + 1 * kD, g2 + 2 * kD, b2 + 2 * kD,
        cA, cB, out, zA);
    blk_kernel<2><<<grid, blk, 0, stream>>>((const uint4*)zA, i16,
        wpack + (2 + 2 * 6) * 64, g1 + 2 * kD, b1 + 2 * kD, g2 + 3 * kD, b2 + 3 * kD,
        cB, nullptr, out, zB);
    blk_kernel<3><<<grid, blk, 0, stream>>>((const uint4*)zB, i16,
        wpack + (2 + 3 * 6) * 64, g1 + 3 * kD, b1 + 3 * kD, nullptr, nullptr,
        nullptr, nullptr, out, nullptr);
}

// Round 4
// 676.082 us; speedup vs baseline: 1.9966x; 1.9966x over previous
//
#include <hip/hip_runtime.h>
#include <hip/hip_fp16.h>
#include <hip/hip_cooperative_groups.h>

namespace cg = cooperative_groups;

namespace {

typedef _Float16 half8 __attribute__((ext_vector_type(8)));
typedef float f32x4 __attribute__((ext_vector_type(4)));
typedef float f32x4v __attribute__((ext_vector_type(4)));

constexpr int kN = 65536;
constexpr int kD = 32;
constexpr int kPts = 2 * kN;                 // 131072 points (B*N)
constexpr int kThreads = 256;                // 4 waves
constexpr int kPtsPerBlk = 64;               // fallback: 16 points per wave
constexpr int kBlocks = kPts / kPtsPerBlk;   // fallback grid: 2048
constexpr int kCoopBlocks = 1024;            // fused grid: 4 blocks/CU co-resident
constexpr int kPtsPerCoop = 128;             // points per fused block (2 chunks of 64)
constexpr int kNumFrags = 24;
static_assert(kCoopBlocks * kPtsPerCoop == kPts, "coop grid must tile points");
static_assert(kN % kPtsPerCoop == 0, "blocks must not straddle batch boundary");

__device__ __forceinline__ float relu_(float v) { return fmaxf(v, 0.f); }
__device__ __forceinline__ float lrelu_(float v) { return v >= 0.f ? v : 0.2f * v; }

// channel permutation induced by the interleaved z-row layout.
__device__ __forceinline__ int pi_(int k) {
    const int c = ((k >> 3) << 2) + ((k & 7) >> 1);
    return (k & 1) ? c + 16 : c;
}

// fallback swizzle (2048 blocks x 64 pts)
__device__ __forceinline__ int swizzled_pbase(int bid) {
    const int xcd   = bid & 7;
    const int slot  = bid >> 3;
    const int batch = xcd >> 2;
    const int local = (xcd & 3) * (kBlocks / 8) + slot;
    return batch * kN + local * kPtsPerBlk;
}

// fused swizzle (1024 blocks x 128 pts): XCDs 0-3 -> batch 0, 4-7 -> batch 1
__device__ __forceinline__ int coop_pbase(int bid) {
    const int xcd   = bid & 7;
    const int slot  = bid >> 3;                    // 0..127
    const int batch = xcd >> 2;
    const int local = (xcd & 3) * 128 + slot;      // 0..511
    return batch * kN + local * kPtsPerCoop;
}

__device__ __forceinline__ void build_wpack(int tid, const float* __restrict__ W2d,
                                            const float* __restrict__ W1d,
                                            uint4* __restrict__ wpack)
{
    for (int id = tid; id < kNumFrags * 64; id += kThreads) {
        const int fid = id >> 6, l = id & 63, n = l & 15, q = l >> 4;
        half8 v;
        if (fid < 2) {
            const int h = fid;
#pragma unroll
            for (int j = 0; j < 8; ++j)
                v[j] = (_Float16)W2d[(q * 8 + j) * kD + h * 16 + n];
        } else {
            const int rel = fid - 2;
            const int layer = (rel < 18) ? rel / 6 : 3;
            const int sub   = (rel < 18) ? rel % 6 : rel - 18;
            if (sub < 4) {
                const int p = sub >> 1, h = sub & 1;
#pragma unroll
                for (int j = 0; j < 8; ++j)
                    v[j] = (_Float16)W1d[layer * 2048 + (p * 32 + pi_(q * 8 + j)) * kD + h * 16 + n];
            } else {
                const int h = sub - 4;
#pragma unroll
                for (int j = 0; j < 8; ++j)
                    v[j] = (_Float16)W2d[(layer + 1) * 1024 + pi_(q * 8 + j) * kD + h * 16 + n];
            }
        }
        wpack[id] = *reinterpret_cast<const uint4*>(&v);
    }
}

// ---------------------------------------------------------------------------
// One layer x one 64-point chunk of the fused kernel. Numerically identical
// to the verified blk_kernel path: gather -> packed fp16 max/mean -> LDS
// bounce -> conv2 MFMA -> fp32 transpose -> epilogue (sacc in LDS, prev in
// regs) -> z-next MFMA. LAYER: 0=first, 1/2=mid, 3=last (writes out).
// ---------------------------------------------------------------------------
template <int LAYER>
__device__ __forceinline__ void layer_chunk(
    const int pbase, const int lpbase, const int lane, const int n, const int q,
    const int base,
    const uint4* __restrict__ zsrc, __half2* __restrict__ znext,
    const uint4* __restrict__ sidx,                    // LDS: packed u16 idx
    const uint4* __restrict__ wf,
    const float* __restrict__ g1v, const float* __restrict__ b1v,
    const float* __restrict__ g2v, const float* __restrict__ b2v,
    float* __restrict__ out,
    f32x4* __restrict__ sacc2,                         // LDS: this thread {s0,s1}
    half8& prevh,
    _Float16 (* __restrict__ gmaxw)[40], _Float16 (* __restrict__ gmeanw)[40],
    float2 (* __restrict__ tbw)[17])
{
    const int point = pbase + n;
    const int gpt = lane >> 2;
    const int gq  = lane & 3;
    const int lgp = lpbase + gpt;
    const uint4 iv0 = sidx[lgp * 2 + 0];
    const uint4 iv1 = sidx[lgp * 2 + 1];

    // phase 1: issue ALL 16 gather loads
    uint4 gbuf[16];
#pragma unroll
    for (int k = 0; k < 16; ++k) {
        unsigned word;
        if (k < 8) word = reinterpret_cast<const unsigned*>(&iv0)[k >> 1];
        else       word = reinterpret_cast<const unsigned*>(&iv1)[(k - 8) >> 1];
        const int row = (k & 1) ? (int)(word >> 16) : (int)(word & 0xFFFFu);
        gbuf[k] = zsrc[(base + row) * 4 + gq];
    }
    // phase 2: packed fp16 reduce
    half8 hmx = (half8)(_Float16)0;
    half8 hsm = (half8)(_Float16)0;
#pragma unroll
    for (int k = 0; k < 16; ++k) {
        const half8 hv = *reinterpret_cast<const half8*>(&gbuf[k]);
        hsm += hv;
#pragma unroll
        for (int c = 0; c < 8; ++c)
            hmx[c] = hmx[c] > hv[c] ? hmx[c] : hv[c];
    }
    {
        const half8 hmn = hsm * (_Float16)0.0625;
        *reinterpret_cast<uint4*>(&gmaxw[gpt][gq * 8]) =
            *reinterpret_cast<const uint4*>(&hmx);
        *reinterpret_cast<uint4*>(&gmeanw[gpt][gq * 8]) =
            *reinterpret_cast<const uint4*>(&hmn);
    }
    __builtin_amdgcn_wave_barrier();

    const half8 amax  = *reinterpret_cast<const half8*>(&gmaxw[n][q * 8]);
    const half8 amean = *reinterpret_cast<const half8*>(&gmeanw[n][q * 8]);

    const uint4 f0 = wf[0 * 64 + lane];
    const uint4 f1 = wf[1 * 64 + lane];
    const uint4 f2 = wf[2 * 64 + lane];
    const uint4 f3 = wf[3 * 64 + lane];
    const half8 bA0 = *reinterpret_cast<const half8*>(&f0);
    const half8 bA1 = *reinterpret_cast<const half8*>(&f1);
    const half8 bB0 = *reinterpret_cast<const half8*>(&f2);
    const half8 bB1 = *reinterpret_cast<const half8*>(&f3);

    f32x4 acc0 = {0.f, 0.f, 0.f, 0.f}, acc1 = {0.f, 0.f, 0.f, 0.f};
    acc0 = __builtin_amdgcn_mfma_f32_16x16x32_f16(amax,  bA0, acc0, 0, 0, 0);
    acc0 = __builtin_amdgcn_mfma_f32_16x16x32_f16(amean, bB0, acc0, 0, 0, 0);
    acc1 = __builtin_amdgcn_mfma_f32_16x16x32_f16(amax,  bA1, acc1, 0, 0, 0);
    acc1 = __builtin_amdgcn_mfma_f32_16x16x32_f16(amean, bB1, acc1, 0, 0, 0);

    const float g10 = g1v[n], g11 = g1v[16 + n];
    const float c10 = b1v[n], c11 = b1v[16 + n];
#pragma unroll
    for (int r = 0; r < 4; ++r) {
        tbw[q * 4 + r][n] = make_float2(fmaf(acc0[r], g10, c10),
                                        fmaf(acc1[r], g11, c11));
    }
    __builtin_amdgcn_wave_barrier();
    float y8[8];
#pragma unroll
    for (int s = 0; s < 4; ++s) {
        const float2 f = tbw[n][q * 4 + s];
        y8[2 * s] = f.x; y8[2 * s + 1] = f.y;
    }

    // ---- epilogue: sacc in LDS, prev in registers ----
    float t8[8];
    if constexpr (LAYER == 0) {
        sacc2[0] = (f32x4){y8[0], y8[2], y8[4], y8[6]};
        sacc2[1] = (f32x4){y8[1], y8[3], y8[5], y8[7]};
#pragma unroll
        for (int c = 0; c < 8; ++c) prevh[c] = (_Float16)y8[c];
#pragma unroll
        for (int c = 0; c < 8; ++c) t8[c] = lrelu_(y8[c]);
    } else if constexpr (LAYER == 1 || LAYER == 2) {
        f32x4 s0 = sacc2[0], s1 = sacc2[1];
        s0.x += y8[0]; s0.y += y8[2]; s0.z += y8[4]; s0.w += y8[6];
        s1.x += y8[1]; s1.y += y8[3]; s1.z += y8[5]; s1.w += y8[7];
        sacc2[0] = s0; sacc2[1] = s1;
#pragma unroll
        for (int c = 0; c < 8; ++c)
            t8[c] = lrelu_(y8[c] + (float)prevh[c]);
#pragma unroll
        for (int c = 0; c < 8; ++c) prevh[c] = (_Float16)y8[c];
    } else {  // LAYER == 3: out = lrelu(sacc + y); nontemporal (zero reuse)
        const f32x4 s0 = sacc2[0], s1 = sacc2[1];
        const int sb0 = point * kD + q * 4;
        const int sb1 = sb0 + 16;
        __builtin_nontemporal_store(
            (f32x4v){lrelu_(s0.x + y8[0]), lrelu_(s0.y + y8[2]),
                     lrelu_(s0.z + y8[4]), lrelu_(s0.w + y8[6])},
            reinterpret_cast<f32x4v*>(out) + (sb0 >> 2));
        __builtin_nontemporal_store(
            (f32x4v){lrelu_(s1.x + y8[1]), lrelu_(s1.y + y8[3]),
                     lrelu_(s1.z + y8[5]), lrelu_(s1.w + y8[7])},
            reinterpret_cast<f32x4v*>(out) + (sb1 >> 2));
        return;
    }

    // ---- z-next MFMA; C-layout-native store (stays cached: reused next layer)
    half8 at;
#pragma unroll
    for (int c = 0; c < 8; ++c) at[c] = (_Float16)t8[c];
    const uint4 f4 = wf[4 * 64 + lane];
    const uint4 f5 = wf[5 * 64 + lane];
    const half8 bz0 = *reinterpret_cast<const half8*>(&f4);
    const half8 bz1 = *reinterpret_cast<const half8*>(&f5);
    f32x4 az0 = {0.f, 0.f, 0.f, 0.f}, az1 = {0.f, 0.f, 0.f, 0.f};
    az0 = __builtin_amdgcn_mfma_f32_16x16x32_f16(at, bz0, az0, 0, 0, 0);
    az1 = __builtin_amdgcn_mfma_f32_16x16x32_f16(at, bz1, az1, 0, 0, 0);

    const float g20 = g2v[n], g21 = g2v[16 + n];
    const float c20 = b2v[n], c21 = b2v[16 + n];
#pragma unroll
    for (int r = 0; r < 4; ++r) {
        const int pm = pbase + q * 4 + r;
        znext[pm * 16 + n] = __floats2half2_rn(relu_(fmaf(az0[r], g20, c20)),
                                               relu_(fmaf(az1[r], g21, c21)));
    }
}

// ---------------------------------------------------------------------------
// Fused cooperative kernel: zprep + 4 blk layers with grid syncs between.
// grid.sync() alone provides the cross-XCD release/acquire (per-block, once).
// R3's per-thread __threadfence() was ~2M whole-L2 wbl2/inv walks -> 1.35 ms.
// ---------------------------------------------------------------------------
__global__ __launch_bounds__(kThreads, 4)
void fused_kernel(const float* __restrict__ x, const int4* __restrict__ idx4,
                  const float* __restrict__ W2d, const float* __restrict__ W1d,
                  const float* __restrict__ g1a, const float* __restrict__ b1a,
                  const float* __restrict__ g2a, const float* __restrict__ b2a,
                  __half2* __restrict__ zA, __half2* __restrict__ zB,
                  uint4* __restrict__ wpack, float* __restrict__ out)
{
    __shared__ __align__(16) _Float16 gmax[4][16][40];      // 5120 B
    __shared__ __align__(16) _Float16 gmean[4][16][40];     // 5120 B
    __shared__ float2 tb[4][16][17];                        // 8704 B
    __shared__ uint4 sidx[kPtsPerCoop * 2];                 // 4096 B
    __shared__ f32x4 saccs[2][kThreads][2];                 // 16384 B -> 39.4 KB total

    const int tid  = threadIdx.x;
    const int w    = tid >> 6;
    const int lane = tid & 63;
    const int n    = lane & 15;
    const int q    = lane >> 4;
    const int blockPbase = coop_pbase(blockIdx.x);
    const int base = blockPbase & ~(kN - 1);

    cg::grid_group grid = cg::this_grid();

    // ---- phase 0: wpack (block 0 only) ----
    if (blockIdx.x == 0) build_wpack(tid, W2d, W1d, wpack);

    // ---- phase 0: pack idx -> LDS (thread t: local point t>>1, half t&1) ----
    {
        const int lp = tid >> 1, h = tid & 1;
        const int p  = blockPbase + lp;
        const int4 a = idx4[p * 4 + 2 * h];
        const int4 b = idx4[p * 4 + 2 * h + 1];
        uint4 o;
        o.x = (unsigned)(a.x & 0xFFFF) | ((unsigned)a.y << 16);
        o.y = (unsigned)(a.z & 0xFFFF) | ((unsigned)a.w << 16);
        o.z = (unsigned)(b.x & 0xFFFF) | ((unsigned)b.y << 16);
        o.w = (unsigned)(b.z & 0xFFFF) | ((unsigned)b.w << 16);
        sidx[lp * 2 + h] = o;
    }

    // ---- phase 0: z1 = relu((x @ W2_0) * g2_0 + b2_0) for both chunks ----
    {
        half8 b0, b1;
#pragma unroll
        for (int j = 0; j < 8; ++j) {
            b0[j] = (_Float16)W2d[(q * 8 + j) * kD + n];
            b1[j] = (_Float16)W2d[(q * 8 + j) * kD + 16 + n];
        }
        const float g20 = g2a[n], g21 = g2a[16 + n];
        const float c20 = b2a[n], c21 = b2a[16 + n];
#pragma unroll
        for (int c = 0; c < 2; ++c) {
            const int pbase = blockPbase + c * 64 + w * 16;
            const int point = pbase + n;
            const float4 x0 = reinterpret_cast<const float4*>(x)[point * 8 + q * 2];
            const float4 x1 = reinterpret_cast<const float4*>(x)[point * 8 + q * 2 + 1];
            half8 ax;
            ax[0] = (_Float16)x0.x; ax[1] = (_Float16)x0.y;
            ax[2] = (_Float16)x0.z; ax[3] = (_Float16)x0.w;
            ax[4] = (_Float16)x1.x; ax[5] = (_Float16)x1.y;
            ax[6] = (_Float16)x1.z; ax[7] = (_Float16)x1.w;
            f32x4 a0 = {0.f, 0.f, 0.f, 0.f}, a1 = {0.f, 0.f, 0.f, 0.f};
            a0 = __builtin_amdgcn_mfma_f32_16x16x32_f16(ax, b0, a0, 0, 0, 0);
            a1 = __builtin_amdgcn_mfma_f32_16x16x32_f16(ax, b1, a1, 0, 0, 0);
#pragma unroll
            for (int r = 0; r < 4; ++r) {
                const int pm = pbase + q * 4 + r;
                zA[pm * 16 + n] = __floats2half2_rn(relu_(fmaf(a0[r], g20, c20)),
                                                    relu_(fmaf(a1[r], g21, c21)));
            }
        }
    }

    grid.sync();

    const int pb0 = blockPbase + w * 16;
    const int pb1 = blockPbase + 64 + w * 16;
    const int lp0 = w * 16;
    const int lp1 = 64 + w * 16;
    half8 phA, phB;

    // ---- layer 0: zA -> zB ----
    layer_chunk<0>(pb0, lp0, lane, n, q, base, (const uint4*)zA, zB, sidx,
                   wpack + (2 + 0 * 6) * 64, g1a, b1a, g2a + 1 * kD, b2a + 1 * kD,
                   out, &saccs[0][tid][0], phA, gmax[w], gmean[w], tb[w]);
    layer_chunk<0>(pb1, lp1, lane, n, q, base, (const uint4*)zA, zB, sidx,
                   wpack + (2 + 0 * 6) * 64, g1a, b1a, g2a + 1 * kD, b2a + 1 * kD,
                   out, &saccs[1][tid][0], phB, gmax[w], gmean[w], tb[w]);
    grid.sync();

    // ---- layer 1: zB -> zA ----
    layer_chunk<1>(pb0, lp0, lane, n, q, base, (const uint4*)zB, zA, sidx,
                   wpack + (2 + 1 * 6) * 64, g1a + 1 * kD, b1a + 1 * kD,
                   g2a + 2 * kD, b2a + 2 * kD,
                   out, &saccs[0][tid][0], phA, gmax[w], gmean[w], tb[w]);
    layer_chunk<1>(pb1, lp1, lane, n, q, base, (const uint4*)zB, zA, sidx,
                   wpack + (2 + 1 * 6) * 64, g1a + 1 * kD, b1a + 1 * kD,
                   g2a + 2 * kD, b2a + 2 * kD,
                   out, &saccs[1][tid][0], phB, gmax[w], gmean[w], tb[w]);
    grid.sync();

    // ---- layer 2: zA -> zB (both chunks gather from zA) ----
    layer_chunk<2>(pb0, lp0, lane, n, q, base, (const uint4*)zA, zB, sidx,
                   wpack + (2 + 2 * 6) * 64, g1a + 2 * kD, b1a + 2 * kD,
                   g2a + 3 * kD, b2a + 3 * kD,
                   out, &saccs[0][tid][0], phA, gmax[w], gmean[w], tb[w]);
    layer_chunk<2>(pb1, lp1, lane, n, q, base, (const uint4*)zA, zB, sidx,
                   wpack + (2 + 2 * 6) * 64, g1a + 2 * kD, b1a + 2 * kD,
                   g2a + 3 * kD, b2a + 3 * kD,
                   out, &saccs[1][tid][0], phB, gmax[w], gmean[w], tb[w]);
    grid.sync();

    // ---- layer 3: zB -> out ----
    layer_chunk<3>(pb0, lp0, lane, n, q, base, (const uint4*)zB, nullptr, sidx,
                   wpack + (2 + 3 * 6) * 64, g1a + 3 * kD, b1a + 3 * kD,
                   nullptr, nullptr,
                   out, &saccs[0][tid][0], phA, gmax[w], gmean[w], tb[w]);
    layer_chunk<3>(pb1, lp1, lane, n, q, base, (const uint4*)zB, nullptr, sidx,
                   wpack + (2 + 3 * 6) * 64, g1a + 3 * kD, b1a + 3 * kD,
                   nullptr, nullptr,
                   out, &saccs[1][tid][0], phB, gmax[w], gmean[w], tb[w]);
}

// ---------------------------------------------------------------------------
// Fallback path: verified 5-dispatch pipeline (171.8 us baseline, no nt).
// ---------------------------------------------------------------------------
__global__ __launch_bounds__(kThreads, 4)
void zprep_kernel(const float* __restrict__ x, const int4* __restrict__ idx4,
                  const float* __restrict__ W2d, const float* __restrict__ W1d,
                  const float* __restrict__ g2v, const float* __restrict__ b2v,
                  __half2* __restrict__ z, uint2* __restrict__ idx16,
                  uint4* __restrict__ wpack)
{
    const int tid = threadIdx.x;
    if (blockIdx.x == 0) build_wpack(tid, W2d, W1d, wpack);
    {
        const int p = blockIdx.x * kPtsPerBlk + (tid >> 2);
        const int part = tid & 3;
        const int4 iv = idx4[p * 4 + part];
        uint2 o;
        o.x = (unsigned)(iv.x & 0xFFFF) | ((unsigned)iv.y << 16);
        o.y = (unsigned)(iv.z & 0xFFFF) | ((unsigned)iv.w << 16);
        idx16[p * 4 + part] = o;
    }
    const int w    = tid >> 6;
    const int lane = tid & 63;
    const int n    = lane & 15;
    const int q    = lane >> 4;
    const int pbase = blockIdx.x * kPtsPerBlk + w * 16;
    const int point = pbase + n;

    const float4 x0 = reinterpret_cast<const float4*>(x)[point * 8 + q * 2];
    const float4 x1 = reinterpret_cast<const float4*>(x)[point * 8 + q * 2 + 1];
    half8 ax;
    ax[0] = (_Float16)x0.x; ax[1] = (_Float16)x0.y;
    ax[2] = (_Float16)x0.z; ax[3] = (_Float16)x0.w;
    ax[4] = (_Float16)x1.x; ax[5] = (_Float16)x1.y;
    ax[6] = (_Float16)x1.z; ax[7] = (_Float16)x1.w;

    half8 b0, b1;
#pragma unroll
    for (int j = 0; j < 8; ++j) {
        b0[j] = (_Float16)W2d[(q * 8 + j) * kD + n];
        b1[j] = (_Float16)W2d[(q * 8 + j) * kD + 16 + n];
    }
    f32x4 a0 = {0.f, 0.f, 0.f, 0.f}, a1 = {0.f, 0.f, 0.f, 0.f};
    a0 = __builtin_amdgcn_mfma_f32_16x16x32_f16(ax, b0, a0, 0, 0, 0);
    a1 = __builtin_amdgcn_mfma_f32_16x16x32_f16(ax, b1, a1, 0, 0, 0);

    const float g20 = g2v[n], g21 = g2v[16 + n];
    const float c20 = b2v[n], c21 = b2v[16 + n];
#pragma unroll
    for (int r = 0; r < 4; ++r) {
        const int pm = pbase + q * 4 + r;
        z[pm * 16 + n] = __floats2half2_rn(relu_(fmaf(a0[r], g20, c20)),
                                           relu_(fmaf(a1[r], g21, c21)));
    }
}

template <int MODE>
__global__ __launch_bounds__(kThreads, 4)
void blk_kernel(const uint4* __restrict__ zsrc, const uint4* __restrict__ idx16,
                const uint4* __restrict__ wfrag,
                const float* __restrict__ g1v, const float* __restrict__ b1v,
                const float* __restrict__ g2v, const float* __restrict__ b2v,
                const uint4* __restrict__ prev, uint4* __restrict__ cur,
                float* __restrict__ sacc, __half2* __restrict__ znext)
{
    __shared__ __align__(16) _Float16 gmax[4][16][40];
    __shared__ __align__(16) _Float16 gmean[4][16][40];
    __shared__ float2 tb[4][16][17];

    const int tid  = threadIdx.x;
    const int w    = tid >> 6;
    const int lane = tid & 63;
    const int n    = lane & 15;
    const int q    = lane >> 4;
    const int blockPbase = swizzled_pbase(blockIdx.x);
    const int pbase = blockPbase + w * 16;
    const int point = pbase + n;
    const int base  = pbase & ~(kN - 1);

    const int sb0 = point * kD + q * 4;
    const int sb1 = sb0 + 16;
    float4 sv0, sv1; uint4 pv;
    if (MODE != 0) {
        sv0 = reinterpret_cast<const float4*>(sacc)[sb0 >> 2];
        sv1 = reinterpret_cast<const float4*>(sacc)[sb1 >> 2];
    }
    if (MODE == 1 || MODE == 2) pv = prev[point * 4 + q];

    const int gpt = lane >> 2;
    const int gq  = lane & 3;
    const int gpoint = pbase + gpt;
    const uint4 iv0 = idx16[gpoint * 2 + 0];
    const uint4 iv1 = idx16[gpoint * 2 + 1];

    uint4 gbuf[16];
#pragma unroll
    for (int k = 0; k < 16; ++k) {
        unsigned word;
        if (k < 8) word = reinterpret_cast<const unsigned*>(&iv0)[k >> 1];
        else       word = reinterpret_cast<const unsigned*>(&iv1)[(k - 8) >> 1];
        const int row = (k & 1) ? (int)(word >> 16) : (int)(word & 0xFFFFu);
        gbuf[k] = zsrc[(base + row) * 4 + gq];
    }
    half8 hmx = (half8)(_Float16)0;
    half8 hsm = (half8)(_Float16)0;
#pragma unroll
    for (int k = 0; k < 16; ++k) {
        const half8 hv = *reinterpret_cast<const half8*>(&gbuf[k]);
        hsm += hv;
#pragma unroll
        for (int c = 0; c < 8; ++c)
            hmx[c] = hmx[c] > hv[c] ? hmx[c] : hv[c];
    }
    {
        const half8 hmn = hsm * (_Float16)0.0625;
        *reinterpret_cast<uint4*>(&gmax[w][gpt][gq * 8]) =
            *reinterpret_cast<const uint4*>(&hmx);
        *reinterpret_cast<uint4*>(&gmean[w][gpt][gq * 8]) =
            *reinterpret_cast<const uint4*>(&hmn);
    }
    __builtin_amdgcn_wave_barrier();

    const half8 amax  = *reinterpret_cast<const half8*>(&gmax[w][n][q * 8]);
    const half8 amean = *reinterpret_cast<const half8*>(&gmean[w][n][q * 8]);

    const uint4 f0 = wfrag[0 * 64 + lane];
    const uint4 f1 = wfrag[1 * 64 + lane];
    const uint4 f2 = wfrag[2 * 64 + lane];
    const uint4 f3 = wfrag[3 * 64 + lane];
    const half8 bA0 = *reinterpret_cast<const half8*>(&f0);
    const half8 bA1 = *reinterpret_cast<const half8*>(&f1);
    const half8 bB0 = *reinterpret_cast<const half8*>(&f2);
    const half8 bB1 = *reinterpret_cast<const half8*>(&f3);

    f32x4 acc0 = {0.f, 0.f, 0.f, 0.f}, acc1 = {0.f, 0.f, 0.f, 0.f};
    acc0 = __builtin_amdgcn_mfma_f32_16x16x32_f16(amax,  bA0, acc0, 0, 0, 0);
    acc0 = __builtin_amdgcn_mfma_f32_16x16x32_f16(amean, bB0, acc0, 0, 0, 0);
    acc1 = __builtin_amdgcn_mfma_f32_16x16x32_f16(amax,  bA1, acc1, 0, 0, 0);
    acc1 = __builtin_amdgcn_mfma_f32_16x16x32_f16(amean, bB1, acc1, 0, 0, 0);

    const float g10 = g1v[n], g11 = g1v[16 + n];
    const float c10 = b1v[n], c11 = b1v[16 + n];
#pragma unroll
    for (int r = 0; r < 4; ++r) {
        tb[w][q * 4 + r][n] = make_float2(fmaf(acc0[r], g10, c10),
                                          fmaf(acc1[r], g11, c11));
    }
    __builtin_amdgcn_wave_barrier();
    float y8[8];
#pragma unroll
    for (int s = 0; s < 4; ++s) {
        const float2 f = tb[w][n][q * 4 + s];
        y8[2 * s] = f.x; y8[2 * s + 1] = f.y;
    }

    float t8[8];
    if (MODE == 0) {
        reinterpret_cast<float4*>(sacc)[sb0 >> 2] = make_float4(y8[0], y8[2], y8[4], y8[6]);
        reinterpret_cast<float4*>(sacc)[sb1 >> 2] = make_float4(y8[1], y8[3], y8[5], y8[7]);
        half8 ch;
#pragma unroll
        for (int c = 0; c < 8; ++c) ch[c] = (_Float16)y8[c];
        cur[point * 4 + q] = *reinterpret_cast<const uint4*>(&ch);
#pragma unroll
        for (int c = 0; c < 8; ++c) t8[c] = lrelu_(y8[c]);
    } else if (MODE == 1 || MODE == 2) {
        sv0.x += y8[0]; sv0.y += y8[2]; sv0.z += y8[4]; sv0.w += y8[6];
        sv1.x += y8[1]; sv1.y += y8[3]; sv1.z += y8[5]; sv1.w += y8[7];
        reinterpret_cast<float4*>(sacc)[sb0 >> 2] = sv0;
        reinterpret_cast<float4*>(sacc)[sb1 >> 2] = sv1;
        const __half2* ph = reinterpret_cast<const __half2*>(&pv);
#pragma unroll
        for (int c = 0; c < 4; ++c) {
            const float2 f = __half22float2(ph[c]);
            t8[2 * c]     = lrelu_(y8[2 * c] + f.x);
            t8[2 * c + 1] = lrelu_(y8[2 * c + 1] + f.y);
        }
        if (MODE == 1) {
            half8 ch;
#pragma unroll
            for (int c = 0; c < 8; ++c) ch[c] = (_Float16)y8[c];
            cur[point * 4 + q] = *reinterpret_cast<const uint4*>(&ch);
        }
    } else {
        reinterpret_cast<float4*>(sacc)[sb0 >> 2] =
            make_float4(lrelu_(sv0.x + y8[0]), lrelu_(sv0.y + y8[2]),
                        lrelu_(sv0.z + y8[4]), lrelu_(sv0.w + y8[6]));
        reinterpret_cast<float4*>(sacc)[sb1 >> 2] =
            make_float4(lrelu_(sv1.x + y8[1]), lrelu_(sv1.y + y8[3]),
                        lrelu_(sv1.z + y8[5]), lrelu_(sv1.w + y8[7]));
        return;
    }

    half8 at;
#pragma unroll
    for (int c = 0; c < 8; ++c) at[c] = (_Float16)t8[c];
    const uint4 f4 = wfrag[4 * 64 + lane];
    const uint4 f5 = wfrag[5 * 64 + lane];
    const half8 bz0 = *reinterpret_cast<const half8*>(&f4);
    const half8 bz1 = *reinterpret_cast<const half8*>(&f5);
    f32x4 az0 = {0.f, 0.f, 0.f, 0.f}, az1 = {0.f, 0.f, 0.f, 0.f};
    az0 = __builtin_amdgcn_mfma_f32_16x16x32_f16(at, bz0, az0, 0, 0, 0);
    az1 = __builtin_amdgcn_mfma_f32_16x16x32_f16(at, bz1, az1, 0, 0, 0);

    const float g20 = g2v[n], g21 = g2v[16 + n];
    const float c20 = b2v[n], c21 = b2v[16 + n];
#pragma unroll
    for (int r = 0; r < 4; ++r) {
        const int pm = pbase + q * 4 + r;
        znext[pm * 16 + n] = __floats2half2_rn(relu_(fmaf(az0[r], g20, c20)),
                                               relu_(fmaf(az1[r], g21, c21)));
    }
}

}  // namespace

extern "C" void kernel_launch(void* const* d_in, const int* in_sizes, int n_in,
                              void* d_out, int out_size, void* d_ws, size_t ws_size,
                              hipStream_t stream)
{
    const float* x   = (const float*)d_in[0];
    const int4*  idx = (const int4*)d_in[1];
    const float* W2d = (const float*)d_in[2];
    const float* g2  = (const float*)d_in[3];
    const float* b2  = (const float*)d_in[4];
    const float* W1d = (const float*)d_in[5];
    const float* g1  = (const float*)d_in[6];
    const float* b1  = (const float*)d_in[7];
    float* out = (float*)d_out;
    char*  ws  = (char*)d_ws;

    constexpr size_t kHalfMap = (size_t)kPts * kD * sizeof(__half);  // 8 MB
    __half2* zA = (__half2*)(ws);
    __half2* zB = (__half2*)(ws + kHalfMap);
    uint4*   cA = (uint4*)(ws + 2 * kHalfMap);
    uint4*   cB = (uint4*)(ws + 3 * kHalfMap);
    uint2*   idx16 = (uint2*)(ws + 4 * kHalfMap);
    uint4*   wpack = (uint4*)(ws + 4 * kHalfMap + (size_t)kPts * 32);

    // ---- fused cooperative path ----
    {
        const float* g1a = g1; const float* b1a = b1;
        const float* g2a = g2; const float* b2a = b2;
        __half2* zAp = zA; __half2* zBp = zB;
        uint4* wpackp = wpack; float* outp = out;
        void* args[] = {(void*)&x, (void*)&idx, (void*)&W2d, (void*)&W1d,
                        (void*)&g1a, (void*)&b1a, (void*)&g2a, (void*)&b2a,
                        (void*)&zAp, (void*)&zBp, (void*)&wpackp, (void*)&outp};
        hipError_t err = hipLaunchCooperativeKernel(
            (const void*)fused_kernel, dim3(kCoopBlocks), dim3(kThreads),
            args, 0, stream);
        if (err == hipSuccess) return;
        (void)hipGetLastError();   // clear sticky error; fall back
    }

    // ---- fallback: verified 5-dispatch pipeline ----
    const dim3 grid(kBlocks), blk(kThreads);
    zprep_kernel<<<grid, blk, 0, stream>>>(x, idx, W2d, W1d, g2, b2,
                                           zA, idx16, wpack);
    const uint4* i16 = (const uint4*)idx16;
    blk_kernel<0><<<grid, blk, 0, stream>>>((const uint4*)zA, i16,
        wpack + (2 + 0 * 6) * 64, g1, b1, g2 + 1 * kD, b2 + 1 * kD,
        nullptr, cA, out, zB);
    blk_kernel<1><<<grid, blk, 0, stream>>>((const uint4*)zB, i16,
        wpack + (2 + 1 * 6) * 64, g1 + 1 * kD, b1 + 1 * kD, g2 + 2 * kD, b2 + 2 * kD,
        cA, cB, out, zA);
    blk_kernel<2><<<grid, blk, 0, stream>>>((const uint4*)zA, i16,
        wpack + (2 + 2 * 6) * 64, g1 + 2 * kD, b1 + 2 * kD, g2 + 3 * kD, b2 + 3 * kD,
        cB, nullptr, out, zB);
    blk_kernel<3><<<grid, blk, 0, stream>>>((const uint4*)zB, i16,
        wpack + (2 + 3 * 6) * 64, g1 + 3 * kD, b1 + 3 * kD, nullptr, nullptr,
        nullptr, nullptr, out, nullptr);
}

// Round 6
// 194.379 us; speedup vs baseline: 6.9446x; 3.4782x over previous
//
#include <hip/hip_runtime.h>
#include <hip/hip_fp16.h>

namespace {

typedef _Float16 half8 __attribute__((ext_vector_type(8)));
typedef float f32x4 __attribute__((ext_vector_type(4)));

// raw ext-vector types for nontemporal builtins
typedef float    f32x4v __attribute__((ext_vector_type(4)));
typedef unsigned u32x4v __attribute__((ext_vector_type(4)));

constexpr int kN = 65536;
constexpr int kD = 32;
constexpr int kPts = 2 * kN;                 // 131072 points (B*N)
constexpr int kThreads = 256;                // 4 waves
constexpr int kPtsPerBlk = 64;               // 16 points per wave
constexpr int kBlocks = kPts / kPtsPerBlk;   // 2048
constexpr int kNumFrags = 24;
static_assert(kBlocks * kPtsPerBlk == kPts, "grid must tile points exactly");
static_assert(kN % kPtsPerBlk == 0, "blocks must not straddle batch boundary");

__device__ __forceinline__ float relu_(float v) { return fmaxf(v, 0.f); }
__device__ __forceinline__ float lrelu_(float v) { return v >= 0.f ? v : 0.2f * v; }

// channel permutation induced by the interleaved z-row layout:
// row = 16 half2 slots, slot n holds (ch n, ch n+16).
__device__ __forceinline__ int pi_(int k) {
    const int c = ((k >> 3) << 2) + ((k & 7) >> 1);
    return (k & 1) ? c + 16 : c;
}

// XCD-aware block swizzle: XCDs 0-3 -> batch 0, XCDs 4-7 -> batch 1
// (per-XCD gather set == 4 MB L2 capacity). [measured R12: -4 us]
__device__ __forceinline__ int swizzled_pbase(int bid) {
    const int xcd   = bid & 7;
    const int slot  = bid >> 3;                           // 0..255
    const int batch = xcd >> 2;
    const int local = (xcd & 3) * (kBlocks / 8) + slot;   // 0..1023
    return batch * kN + local * kPtsPerBlk;
}

// ---------------------------------------------------------------------------
// zprep: z1 = relu((x @ W2_0) * g2_0 + b2_0) (interleaved fp16), packs idx
// to u16 pairs, and (block 0 only) builds the fp16 B-fragment bank.
// (kept byte-identical to the 171.8/174 us verified baseline)
// ---------------------------------------------------------------------------
__global__ __launch_bounds__(kThreads, 4)
void zprep_kernel(const float* __restrict__ x, const int4* __restrict__ idx4,
                  const float* __restrict__ W2d, const float* __restrict__ W1d,
                  const float* __restrict__ g2v, const float* __restrict__ b2v,
                  __half2* __restrict__ z, uint2* __restrict__ idx16,
                  uint4* __restrict__ wpack)
{
    const int tid = threadIdx.x;
    if (blockIdx.x == 0) {
        for (int id = tid; id < kNumFrags * 64; id += kThreads) {
            const int fid = id >> 6, l = id & 63, n = l & 15, q = l >> 4;
            half8 v;
            if (fid < 2) {
                const int h = fid;
#pragma unroll
                for (int j = 0; j < 8; ++j)
                    v[j] = (_Float16)W2d[(q * 8 + j) * kD + h * 16 + n];
            } else {
                const int rel = fid - 2;
                const int layer = (rel < 18) ? rel / 6 : 3;
                const int sub   = (rel < 18) ? rel % 6 : rel - 18;
                if (sub < 4) {
                    const int p = sub >> 1, h = sub & 1;
#pragma unroll
                    for (int j = 0; j < 8; ++j)
                        v[j] = (_Float16)W1d[layer * 2048 + (p * 32 + pi_(q * 8 + j)) * kD + h * 16 + n];
                } else {
                    const int h = sub - 4;
#pragma unroll
                    for (int j = 0; j < 8; ++j)
                        v[j] = (_Float16)W2d[(layer + 1) * 1024 + pi_(q * 8 + j) * kD + h * 16 + n];
                }
            }
            wpack[id] = *reinterpret_cast<const uint4*>(&v);
        }
    }
    {
        const int p = blockIdx.x * kPtsPerBlk + (tid >> 2);
        const int part = tid & 3;
        const int4 iv = idx4[p * 4 + part];
        uint2 o;
        o.x = (unsigned)(iv.x & 0xFFFF) | ((unsigned)iv.y << 16);
        o.y = (unsigned)(iv.z & 0xFFFF) | ((unsigned)iv.w << 16);
        idx16[p * 4 + part] = o;
    }
    const int w    = tid >> 6;
    const int lane = tid & 63;
    const int n    = lane & 15;
    const int q    = lane >> 4;
    const int pbase = blockIdx.x * kPtsPerBlk + w * 16;
    const int point = pbase + n;

    const float4 x0 = reinterpret_cast<const float4*>(x)[point * 8 + q * 2];
    const float4 x1 = reinterpret_cast<const float4*>(x)[point * 8 + q * 2 + 1];
    half8 ax;
    ax[0] = (_Float16)x0.x; ax[1] = (_Float16)x0.y;
    ax[2] = (_Float16)x0.z; ax[3] = (_Float16)x0.w;
    ax[4] = (_Float16)x1.x; ax[5] = (_Float16)x1.y;
    ax[6] = (_Float16)x1.z; ax[7] = (_Float16)x1.w;

    half8 b0, b1;
#pragma unroll
    for (int j = 0; j < 8; ++j) {
        b0[j] = (_Float16)W2d[(q * 8 + j) * kD + n];
        b1[j] = (_Float16)W2d[(q * 8 + j) * kD + 16 + n];
    }
    f32x4 a0 = {0.f, 0.f, 0.f, 0.f}, a1 = {0.f, 0.f, 0.f, 0.f};
    a0 = __builtin_amdgcn_mfma_f32_16x16x32_f16(ax, b0, a0, 0, 0, 0);
    a1 = __builtin_amdgcn_mfma_f32_16x16x32_f16(ax, b1, a1, 0, 0, 0);

    const float g20 = g2v[n], g21 = g2v[16 + n];
    const float c20 = b2v[n], c21 = b2v[16 + n];
#pragma unroll
    for (int r = 0; r < 4; ++r) {
        const int pm = pbase + q * 4 + r;      // C/D row m = q*4 + r
        z[pm * 16 + n] = __floats2half2_rn(relu_(fmaf(a0[r], g20, c20)),
                                           relu_(fmaf(a1[r], g21, c21)));
    }
}

// ---------------------------------------------------------------------------
// blk: identical structure to the 174 us baseline. ONE change [R5/R6]: the
// linear streaming buffers (sacc r/w, prev read, cur write, final out write)
// are nontemporal so they stop displacing the z gather map from L2/IC.
// znext / z stores and all gather reads stay CACHED (R1 showed nt on znext
// pushes the next layer's gather map out of IC -> catastrophic).
// MODE: 0=first, 1=mid(+cur), 2=mid, 3=last.
// ---------------------------------------------------------------------------
template <int MODE>
__global__ __launch_bounds__(kThreads, 4)
void blk_kernel(const uint4* __restrict__ zsrc, const uint4* __restrict__ idx16,
                const uint4* __restrict__ wfrag,
                const float* __restrict__ g1v, const float* __restrict__ b1v,
                const float* __restrict__ g2v, const float* __restrict__ b2v,
                const uint4* __restrict__ prev, uint4* __restrict__ cur,
                float* __restrict__ sacc, __half2* __restrict__ znext)
{
    __shared__ __align__(16) _Float16 gmax[4][16][40];   // 5120 B
    __shared__ __align__(16) _Float16 gmean[4][16][40];  // 5120 B
    __shared__ float2 tb[4][16][17];                     // 8704 B

    const int tid  = threadIdx.x;
    const int w    = tid >> 6;
    const int lane = tid & 63;
    const int n    = lane & 15;
    const int q    = lane >> 4;
    const int blockPbase = swizzled_pbase(blockIdx.x);
    const int pbase = blockPbase + w * 16;
    const int point = pbase + n;
    const int base  = pbase & ~(kN - 1);       // batch offset (wave-uniform)

    // ---- hoisted independent epilogue loads (hide under the gather) ----
    const int sb0 = point * kD + q * 4;
    const int sb1 = sb0 + 16;
    f32x4v sv0, sv1; u32x4v pv;
    if (MODE != 0) {
        sv0 = __builtin_nontemporal_load(
            reinterpret_cast<const f32x4v*>(sacc) + (sb0 >> 2));
        sv1 = __builtin_nontemporal_load(
            reinterpret_cast<const f32x4v*>(sacc) + (sb1 >> 2));
    }
    if (MODE == 1 || MODE == 2)
        pv = __builtin_nontemporal_load(
            reinterpret_cast<const u32x4v*>(prev) + point * 4 + q);

    // ---- gather phase: lane = 4*gpt + gq (adjacent quads per point) ----
    const int gpt = lane >> 2;
    const int gq  = lane & 3;
    const int gpoint = pbase + gpt;
    const uint4 iv0 = idx16[gpoint * 2 + 0];   // 4 lanes same addr -> broadcast
    const uint4 iv1 = idx16[gpoint * 2 + 1];

    // phase 1: issue ALL 16 loads (live in gbuf -> back-to-back issue)
    uint4 gbuf[16];
#pragma unroll
    for (int k = 0; k < 16; ++k) {
        unsigned word;
        if (k < 8) word = reinterpret_cast<const unsigned*>(&iv0)[k >> 1];
        else       word = reinterpret_cast<const unsigned*>(&iv1)[(k - 8) >> 1];
        const int row = (k & 1) ? (int)(word >> 16) : (int)(word & 0xFFFFu);
        gbuf[k] = zsrc[(base + row) * 4 + gq];  // lanes 4p..4p+3: one 64 B line
    }
    // phase 2: packed fp16 reduce (consumption of k overlaps loads k+1..15)
    half8 hmx = (half8)(_Float16)0;            // relu output >= 0
    half8 hsm = (half8)(_Float16)0;
#pragma unroll
    for (int k = 0; k < 16; ++k) {
        const half8 hv = *reinterpret_cast<const half8*>(&gbuf[k]);
        hsm += hv;                                     // v_pk_add_f16 x4
#pragma unroll
        for (int c = 0; c < 8; ++c)
            hmx[c] = hmx[c] > hv[c] ? hmx[c] : hv[c];  // v_max_f16
    }
    {
        const half8 hmn = hsm * (_Float16)0.0625;
        *reinterpret_cast<uint4*>(&gmax[w][gpt][gq * 8]) =
            *reinterpret_cast<const uint4*>(&hmx);
        *reinterpret_cast<uint4*>(&gmean[w][gpt][gq * 8]) =
            *reinterpret_cast<const uint4*>(&hmn);
    }
    __builtin_amdgcn_wave_barrier();   // same wave writes & reads; DS wave-ordered

    // ---- A-frag lanes (n = point, q = k-quarter) pick up their fragments
    const half8 amax  = *reinterpret_cast<const half8*>(&gmax[w][n][q * 8]);
    const half8 amean = *reinterpret_cast<const half8*>(&gmean[w][n][q * 8]);

    const uint4 f0 = wfrag[0 * 64 + lane];
    const uint4 f1 = wfrag[1 * 64 + lane];
    const uint4 f2 = wfrag[2 * 64 + lane];
    const uint4 f3 = wfrag[3 * 64 + lane];
    const half8 bA0 = *reinterpret_cast<const half8*>(&f0);
    const half8 bA1 = *reinterpret_cast<const half8*>(&f1);
    const half8 bB0 = *reinterpret_cast<const half8*>(&f2);
    const half8 bB1 = *reinterpret_cast<const half8*>(&f3);

    // ---- conv2 MFMA ----
    f32x4 acc0 = {0.f, 0.f, 0.f, 0.f}, acc1 = {0.f, 0.f, 0.f, 0.f};
    acc0 = __builtin_amdgcn_mfma_f32_16x16x32_f16(amax,  bA0, acc0, 0, 0, 0);
    acc0 = __builtin_amdgcn_mfma_f32_16x16x32_f16(amean, bB0, acc0, 0, 0, 0);
    acc1 = __builtin_amdgcn_mfma_f32_16x16x32_f16(amax,  bA1, acc1, 0, 0, 0);
    acc1 = __builtin_amdgcn_mfma_f32_16x16x32_f16(amean, bB1, acc1, 0, 0, 0);

    const float g10 = g1v[n], g11 = g1v[16 + n];
    const float c10 = b1v[n], c11 = b1v[16 + n];
#pragma unroll
    for (int r = 0; r < 4; ++r) {
        tb[w][q * 4 + r][n] = make_float2(fmaf(acc0[r], g10, c10),
                                          fmaf(acc1[r], g11, c11));
    }
    __builtin_amdgcn_wave_barrier();
    float y8[8];
#pragma unroll
    for (int s = 0; s < 4; ++s) {
        const float2 f = tb[w][n][q * 4 + s];
        y8[2 * s] = f.x; y8[2 * s + 1] = f.y;
    }

    // ---- A-layout epilogue (coalesced 16 B global I/O; streaming = nt) ----
    float t8[8];
    if (MODE == 0) {
        __builtin_nontemporal_store((f32x4v){y8[0], y8[2], y8[4], y8[6]},
            reinterpret_cast<f32x4v*>(sacc) + (sb0 >> 2));
        __builtin_nontemporal_store((f32x4v){y8[1], y8[3], y8[5], y8[7]},
            reinterpret_cast<f32x4v*>(sacc) + (sb1 >> 2));
        half8 ch;
#pragma unroll
        for (int c = 0; c < 8; ++c) ch[c] = (_Float16)y8[c];
        __builtin_nontemporal_store(*reinterpret_cast<const u32x4v*>(&ch),
            reinterpret_cast<u32x4v*>(cur) + point * 4 + q);
#pragma unroll
        for (int c = 0; c < 8; ++c) t8[c] = lrelu_(y8[c]);
    } else if (MODE == 1 || MODE == 2) {
        sv0.x += y8[0]; sv0.y += y8[2]; sv0.z += y8[4]; sv0.w += y8[6];
        sv1.x += y8[1]; sv1.y += y8[3]; sv1.z += y8[5]; sv1.w += y8[7];
        __builtin_nontemporal_store(sv0,
            reinterpret_cast<f32x4v*>(sacc) + (sb0 >> 2));
        __builtin_nontemporal_store(sv1,
            reinterpret_cast<f32x4v*>(sacc) + (sb1 >> 2));
        const __half2* ph = reinterpret_cast<const __half2*>(&pv);
#pragma unroll
        for (int c = 0; c < 4; ++c) {
            const float2 f = __half22float2(ph[c]);
            t8[2 * c]     = lrelu_(y8[2 * c] + f.x);
            t8[2 * c + 1] = lrelu_(y8[2 * c + 1] + f.y);
        }
        if (MODE == 1) {
            half8 ch;
#pragma unroll
            for (int c = 0; c < 8; ++c) ch[c] = (_Float16)y8[c];
            __builtin_nontemporal_store(*reinterpret_cast<const u32x4v*>(&ch),
                reinterpret_cast<u32x4v*>(cur) + point * 4 + q);
        }
    } else {  // MODE == 3
        __builtin_nontemporal_store(
            (f32x4v){lrelu_(sv0.x + y8[0]), lrelu_(sv0.y + y8[2]),
                     lrelu_(sv0.z + y8[4]), lrelu_(sv0.w + y8[6])},
            reinterpret_cast<f32x4v*>(sacc) + (sb0 >> 2));
        __builtin_nontemporal_store(
            (f32x4v){lrelu_(sv1.x + y8[1]), lrelu_(sv1.y + y8[3]),
                     lrelu_(sv1.z + y8[5]), lrelu_(sv1.w + y8[7])},
            reinterpret_cast<f32x4v*>(sacc) + (sb1 >> 2));
        return;
    }

    // ---- z-next MFMA; C-layout-native store (CACHED: next layer gathers it)
    half8 at;
#pragma unroll
    for (int c = 0; c < 8; ++c) at[c] = (_Float16)t8[c];
    const uint4 f4 = wfrag[4 * 64 + lane];
    const uint4 f5 = wfrag[5 * 64 + lane];
    const half8 bz0 = *reinterpret_cast<const half8*>(&f4);
    const half8 bz1 = *reinterpret_cast<const half8*>(&f5);
    f32x4 az0 = {0.f, 0.f, 0.f, 0.f}, az1 = {0.f, 0.f, 0.f, 0.f};
    az0 = __builtin_amdgcn_mfma_f32_16x16x32_f16(at, bz0, az0, 0, 0, 0);
    az1 = __builtin_amdgcn_mfma_f32_16x16x32_f16(at, bz1, az1, 0, 0, 0);

    const float g20 = g2v[n], g21 = g2v[16 + n];
    const float c20 = b2v[n], c21 = b2v[16 + n];
#pragma unroll
    for (int r = 0; r < 4; ++r) {
        const int pm = pbase + q * 4 + r;
        znext[pm * 16 + n] = __floats2half2_rn(relu_(fmaf(az0[r], g20, c20)),
                                               relu_(fmaf(az1[r], g21, c21)));
    }
}

}  // namespace

extern "C" void kernel_launch(void* const* d_in, const int* in_sizes, int n_in,
                              void* d_out, int out_size, void* d_ws, size_t ws_size,
                              hipStream_t stream)
{
    const float* x   = (const float*)d_in[0];
    const int4*  idx = (const int4*)d_in[1];
    const float* W2d = (const float*)d_in[2];
    const float* g2  = (const float*)d_in[3];
    const float* b2  = (const float*)d_in[4];
    const float* W1d = (const float*)d_in[5];
    const float* g1  = (const float*)d_in[6];
    const float* b1  = (const float*)d_in[7];
    float* out = (float*)d_out;     // doubles as sacc between dispatches
    char*  ws  = (char*)d_ws;

    constexpr size_t kHalfMap = (size_t)kPts * kD * sizeof(__half);  // 8 MB
    __half2* zA = (__half2*)(ws);
    __half2* zB = (__half2*)(ws + kHalfMap);
    uint4*   cA = (uint4*)(ws + 2 * kHalfMap);                 // x1 (fp16, pi order)
    uint4*   cB = (uint4*)(ws + 3 * kHalfMap);                 // x2 (fp16, pi order)
    uint2*   idx16 = (uint2*)(ws + 4 * kHalfMap);              // 4 MB
    uint4*   wpack = (uint4*)(ws + 4 * kHalfMap + (size_t)kPts * 32);  // 24 KB

    const dim3 grid(kBlocks), blk(kThreads);
    zprep_kernel<<<grid, blk, 0, stream>>>(x, idx, W2d, W1d, g2, b2,
                                           zA, idx16, wpack);

    const uint4* i16 = (const uint4*)idx16;
    blk_kernel<0><<<grid, blk, 0, stream>>>((const uint4*)zA, i16,
        wpack + (2 + 0 * 6) * 64, g1, b1, g2 + 1 * kD, b2 + 1 * kD,
        nullptr, cA, out, zB);
    blk_kernel<1><<<grid, blk, 0, stream>>>((const uint4*)zB, i16,
        wpack + (2 + 1 * 6) * 64, g1 + 1 * kD, b1 + 1 * kD, g2 + 2 * kD, b2 + 2 * kD,
        cA, cB, out, zA);
    blk_kernel<2><<<grid, blk, 0, stream>>>((const uint4*)zA, i16,
        wpack + (2 + 2 * 6) * 64, g1 + 2 * kD, b1 + 2 * kD, g2 + 3 * kD, b2 + 3 * kD,
        cB, nullptr, out, zB);
    blk_kernel<3><<<grid, blk, 0, stream>>>((const uint4*)zB, i16,
        wpack + (2 + 3 * 6) * 64, g1 + 3 * kD, b1 + 3 * kD, nullptr, nullptr,
        nullptr, nullptr, out, nullptr);
}

// Round 7
// 172.724 us; speedup vs baseline: 7.8152x; 1.1254x over previous
//
#include <hip/hip_runtime.h>
#include <hip/hip_fp16.h>

namespace {

typedef _Float16 half8 __attribute__((ext_vector_type(8)));
typedef float f32x4 __attribute__((ext_vector_type(4)));

constexpr int kN = 65536;
constexpr int kD = 32;
constexpr int kPts = 2 * kN;                 // 131072 points (B*N)
constexpr int kThreads = 256;                // 4 waves
constexpr int kPtsPerBlk = 64;               // 16 points per wave
constexpr int kBlocks = kPts / kPtsPerBlk;   // 2048
constexpr int kNumFrags = 24;
static_assert(kBlocks * kPtsPerBlk == kPts, "grid must tile points exactly");
static_assert(kN % kPtsPerBlk == 0, "blocks must not straddle batch boundary");

__device__ __forceinline__ float relu_(float v) { return fmaxf(v, 0.f); }
__device__ __forceinline__ float lrelu_(float v) { return v >= 0.f ? v : 0.2f * v; }

// channel permutation induced by the interleaved z-row layout:
// row = 16 half2 slots, slot n holds (ch n, ch n+16).
__device__ __forceinline__ int pi_(int k) {
    const int c = ((k >> 3) << 2) + ((k & 7) >> 1);
    return (k & 1) ? c + 16 : c;
}

// XCD-aware block swizzle: XCDs 0-3 -> batch 0, XCDs 4-7 -> batch 1
// (per-XCD gather set == 4 MB L2 capacity). [measured R12: -4 us]
__device__ __forceinline__ int swizzled_pbase(int bid) {
    const int xcd   = bid & 7;
    const int slot  = bid >> 3;                           // 0..255
    const int batch = xcd >> 2;
    const int local = (xcd & 3) * (kBlocks / 8) + slot;   // 0..1023
    return batch * kN + local * kPtsPerBlk;
}

// ---------------------------------------------------------------------------
// zprep: z1 = relu((x @ W2_0) * g2_0 + b2_0) (interleaved fp16), packs idx
// to u16 pairs, and (block 0 only) builds the fp16 B-fragment bank.
// (byte-identical to the verified 174 us baseline)
// ---------------------------------------------------------------------------
__global__ __launch_bounds__(kThreads, 4)
void zprep_kernel(const float* __restrict__ x, const int4* __restrict__ idx4,
                  const float* __restrict__ W2d, const float* __restrict__ W1d,
                  const float* __restrict__ g2v, const float* __restrict__ b2v,
                  __half2* __restrict__ z, uint2* __restrict__ idx16,
                  uint4* __restrict__ wpack)
{
    const int tid = threadIdx.x;
    if (blockIdx.x == 0) {
        for (int id = tid; id < kNumFrags * 64; id += kThreads) {
            const int fid = id >> 6, l = id & 63, n = l & 15, q = l >> 4;
            half8 v;
            if (fid < 2) {
                const int h = fid;
#pragma unroll
                for (int j = 0; j < 8; ++j)
                    v[j] = (_Float16)W2d[(q * 8 + j) * kD + h * 16 + n];
            } else {
                const int rel = fid - 2;
                const int layer = (rel < 18) ? rel / 6 : 3;
                const int sub   = (rel < 18) ? rel % 6 : rel - 18;
                if (sub < 4) {
                    const int p = sub >> 1, h = sub & 1;
#pragma unroll
                    for (int j = 0; j < 8; ++j)
                        v[j] = (_Float16)W1d[layer * 2048 + (p * 32 + pi_(q * 8 + j)) * kD + h * 16 + n];
                } else {
                    const int h = sub - 4;
#pragma unroll
                    for (int j = 0; j < 8; ++j)
                        v[j] = (_Float16)W2d[(layer + 1) * 1024 + pi_(q * 8 + j) * kD + h * 16 + n];
                }
            }
            wpack[id] = *reinterpret_cast<const uint4*>(&v);
        }
    }
    {
        const int p = blockIdx.x * kPtsPerBlk + (tid >> 2);
        const int part = tid & 3;
        const int4 iv = idx4[p * 4 + part];
        uint2 o;
        o.x = (unsigned)(iv.x & 0xFFFF) | ((unsigned)iv.y << 16);
        o.y = (unsigned)(iv.z & 0xFFFF) | ((unsigned)iv.w << 16);
        idx16[p * 4 + part] = o;
    }
    const int w    = tid >> 6;
    const int lane = tid & 63;
    const int n    = lane & 15;
    const int q    = lane >> 4;
    const int pbase = blockIdx.x * kPtsPerBlk + w * 16;
    const int point = pbase + n;

    const float4 x0 = reinterpret_cast<const float4*>(x)[point * 8 + q * 2];
    const float4 x1 = reinterpret_cast<const float4*>(x)[point * 8 + q * 2 + 1];
    half8 ax;
    ax[0] = (_Float16)x0.x; ax[1] = (_Float16)x0.y;
    ax[2] = (_Float16)x0.z; ax[3] = (_Float16)x0.w;
    ax[4] = (_Float16)x1.x; ax[5] = (_Float16)x1.y;
    ax[6] = (_Float16)x1.z; ax[7] = (_Float16)x1.w;

    half8 b0, b1;
#pragma unroll
    for (int j = 0; j < 8; ++j) {
        b0[j] = (_Float16)W2d[(q * 8 + j) * kD + n];
        b1[j] = (_Float16)W2d[(q * 8 + j) * kD + 16 + n];
    }
    f32x4 a0 = {0.f, 0.f, 0.f, 0.f}, a1 = {0.f, 0.f, 0.f, 0.f};
    a0 = __builtin_amdgcn_mfma_f32_16x16x32_f16(ax, b0, a0, 0, 0, 0);
    a1 = __builtin_amdgcn_mfma_f32_16x16x32_f16(ax, b1, a1, 0, 0, 0);

    const float g20 = g2v[n], g21 = g2v[16 + n];
    const float c20 = b2v[n], c21 = b2v[16 + n];
#pragma unroll
    for (int r = 0; r < 4; ++r) {
        const int pm = pbase + q * 4 + r;      // C/D row m = q*4 + r
        z[pm * 16 + n] = __floats2half2_rn(relu_(fmaf(a0[r], g20, c20)),
                                           relu_(fmaf(a1[r], g21, c21)));
    }
}

// ---------------------------------------------------------------------------
// blk: byte-identical structure to the verified 174 us baseline (no nt —
// R1/R6 showed nt regresses: every buffer here is cross-dispatch reused).
// ONE change [R7]: __launch_bounds__(256, 5) -> 20 waves/CU (was 16),
// VGPR cap 102 (peak live ~95, 16-deep gather should still fit).
// More resident waves = more outstanding IC gather requests per CU.
// MODE: 0=first, 1=mid(+cur), 2=mid, 3=last.
// ---------------------------------------------------------------------------
template <int MODE>
__global__ __launch_bounds__(kThreads, 5)
void blk_kernel(const uint4* __restrict__ zsrc, const uint4* __restrict__ idx16,
                const uint4* __restrict__ wfrag,
                const float* __restrict__ g1v, const float* __restrict__ b1v,
                const float* __restrict__ g2v, const float* __restrict__ b2v,
                const uint4* __restrict__ prev, uint4* __restrict__ cur,
                float* __restrict__ sacc, __half2* __restrict__ znext)
{
    __shared__ __align__(16) _Float16 gmax[4][16][40];   // 5120 B
    __shared__ __align__(16) _Float16 gmean[4][16][40];  // 5120 B
    __shared__ float2 tb[4][16][17];                     // 8704 B

    const int tid  = threadIdx.x;
    const int w    = tid >> 6;
    const int lane = tid & 63;
    const int n    = lane & 15;
    const int q    = lane >> 4;
    const int blockPbase = swizzled_pbase(blockIdx.x);
    const int pbase = blockPbase + w * 16;
    const int point = pbase + n;
    const int base  = pbase & ~(kN - 1);       // batch offset (wave-uniform)

    // ---- hoisted independent epilogue loads (hide under the gather) ----
    const int sb0 = point * kD + q * 4;
    const int sb1 = sb0 + 16;
    float4 sv0, sv1; uint4 pv;
    if (MODE != 0) {
        sv0 = reinterpret_cast<const float4*>(sacc)[sb0 >> 2];
        sv1 = reinterpret_cast<const float4*>(sacc)[sb1 >> 2];
    }
    if (MODE == 1 || MODE == 2) pv = prev[point * 4 + q];

    // ---- gather phase: lane = 4*gpt + gq (adjacent quads per point) ----
    const int gpt = lane >> 2;
    const int gq  = lane & 3;
    const int gpoint = pbase + gpt;
    const uint4 iv0 = idx16[gpoint * 2 + 0];   // 4 lanes same addr -> broadcast
    const uint4 iv1 = idx16[gpoint * 2 + 1];

    // phase 1: issue ALL 16 loads (live in gbuf -> back-to-back issue)
    uint4 gbuf[16];
#pragma unroll
    for (int k = 0; k < 16; ++k) {
        unsigned word;
        if (k < 8) word = reinterpret_cast<const unsigned*>(&iv0)[k >> 1];
        else       word = reinterpret_cast<const unsigned*>(&iv1)[(k - 8) >> 1];
        const int row = (k & 1) ? (int)(word >> 16) : (int)(word & 0xFFFFu);
        gbuf[k] = zsrc[(base + row) * 4 + gq];  // lanes 4p..4p+3: one 64 B line
    }
    // phase 2: packed fp16 reduce (consumption of k overlaps loads k+1..15)
    half8 hmx = (half8)(_Float16)0;            // relu output >= 0
    half8 hsm = (half8)(_Float16)0;
#pragma unroll
    for (int k = 0; k < 16; ++k) {
        const half8 hv = *reinterpret_cast<const half8*>(&gbuf[k]);
        hsm += hv;                                     // v_pk_add_f16 x4
#pragma unroll
        for (int c = 0; c < 8; ++c)
            hmx[c] = hmx[c] > hv[c] ? hmx[c] : hv[c];  // v_max_f16
    }
    {
        const half8 hmn = hsm * (_Float16)0.0625;
        *reinterpret_cast<uint4*>(&gmax[w][gpt][gq * 8]) =
            *reinterpret_cast<const uint4*>(&hmx);
        *reinterpret_cast<uint4*>(&gmean[w][gpt][gq * 8]) =
            *reinterpret_cast<const uint4*>(&hmn);
    }
    __builtin_amdgcn_wave_barrier();   // same wave writes & reads; DS wave-ordered

    // ---- A-frag lanes (n = point, q = k-quarter) pick up their fragments
    const half8 amax  = *reinterpret_cast<const half8*>(&gmax[w][n][q * 8]);
    const half8 amean = *reinterpret_cast<const half8*>(&gmean[w][n][q * 8]);

    const uint4 f0 = wfrag[0 * 64 + lane];
    const uint4 f1 = wfrag[1 * 64 + lane];
    const uint4 f2 = wfrag[2 * 64 + lane];
    const uint4 f3 = wfrag[3 * 64 + lane];
    const half8 bA0 = *reinterpret_cast<const half8*>(&f0);
    const half8 bA1 = *reinterpret_cast<const half8*>(&f1);
    const half8 bB0 = *reinterpret_cast<const half8*>(&f2);
    const half8 bB1 = *reinterpret_cast<const half8*>(&f3);

    // ---- conv2 MFMA ----
    f32x4 acc0 = {0.f, 0.f, 0.f, 0.f}, acc1 = {0.f, 0.f, 0.f, 0.f};
    acc0 = __builtin_amdgcn_mfma_f32_16x16x32_f16(amax,  bA0, acc0, 0, 0, 0);
    acc0 = __builtin_amdgcn_mfma_f32_16x16x32_f16(amean, bB0, acc0, 0, 0, 0);
    acc1 = __builtin_amdgcn_mfma_f32_16x16x32_f16(amax,  bA1, acc1, 0, 0, 0);
    acc1 = __builtin_amdgcn_mfma_f32_16x16x32_f16(amean, bB1, acc1, 0, 0, 0);

    const float g10 = g1v[n], g11 = g1v[16 + n];
    const float c10 = b1v[n], c11 = b1v[16 + n];
#pragma unroll
    for (int r = 0; r < 4; ++r) {
        tb[w][q * 4 + r][n] = make_float2(fmaf(acc0[r], g10, c10),
                                          fmaf(acc1[r], g11, c11));
    }
    __builtin_amdgcn_wave_barrier();
    float y8[8];
#pragma unroll
    for (int s = 0; s < 4; ++s) {
        const float2 f = tb[w][n][q * 4 + s];
        y8[2 * s] = f.x; y8[2 * s + 1] = f.y;
    }

    // ---- A-layout epilogue (coalesced 16 B global I/O) ----
    float t8[8];
    if (MODE == 0) {
        reinterpret_cast<float4*>(sacc)[sb0 >> 2] = make_float4(y8[0], y8[2], y8[4], y8[6]);
        reinterpret_cast<float4*>(sacc)[sb1 >> 2] = make_float4(y8[1], y8[3], y8[5], y8[7]);
        half8 ch;
#pragma unroll
        for (int c = 0; c < 8; ++c) ch[c] = (_Float16)y8[c];
        cur[point * 4 + q] = *reinterpret_cast<const uint4*>(&ch);
#pragma unroll
        for (int c = 0; c < 8; ++c) t8[c] = lrelu_(y8[c]);
    } else if (MODE == 1 || MODE == 2) {
        sv0.x += y8[0]; sv0.y += y8[2]; sv0.z += y8[4]; sv0.w += y8[6];
        sv1.x += y8[1]; sv1.y += y8[3]; sv1.z += y8[5]; sv1.w += y8[7];
        reinterpret_cast<float4*>(sacc)[sb0 >> 2] = sv0;
        reinterpret_cast<float4*>(sacc)[sb1 >> 2] = sv1;
        const __half2* ph = reinterpret_cast<const __half2*>(&pv);
#pragma unroll
        for (int c = 0; c < 4; ++c) {
            const float2 f = __half22float2(ph[c]);
            t8[2 * c]     = lrelu_(y8[2 * c] + f.x);
            t8[2 * c + 1] = lrelu_(y8[2 * c + 1] + f.y);
        }
        if (MODE == 1) {
            half8 ch;
#pragma unroll
            for (int c = 0; c < 8; ++c) ch[c] = (_Float16)y8[c];
            cur[point * 4 + q] = *reinterpret_cast<const uint4*>(&ch);
        }
    } else {  // MODE == 3
        reinterpret_cast<float4*>(sacc)[sb0 >> 2] =
            make_float4(lrelu_(sv0.x + y8[0]), lrelu_(sv0.y + y8[2]),
                        lrelu_(sv0.z + y8[4]), lrelu_(sv0.w + y8[6]));
        reinterpret_cast<float4*>(sacc)[sb1 >> 2] =
            make_float4(lrelu_(sv1.x + y8[1]), lrelu_(sv1.y + y8[3]),
                        lrelu_(sv1.z + y8[5]), lrelu_(sv1.w + y8[7]));
        return;
    }

    // ---- z-next MFMA; C-layout-native store ----
    half8 at;
#pragma unroll
    for (int c = 0; c < 8; ++c) at[c] = (_Float16)t8[c];
    const uint4 f4 = wfrag[4 * 64 + lane];
    const uint4 f5 = wfrag[5 * 64 + lane];
    const half8 bz0 = *reinterpret_cast<const half8*>(&f4);
    const half8 bz1 = *reinterpret_cast<const half8*>(&f5);
    f32x4 az0 = {0.f, 0.f, 0.f, 0.f}, az1 = {0.f, 0.f, 0.f, 0.f};
    az0 = __builtin_amdgcn_mfma_f32_16x16x32_f16(at, bz0, az0, 0, 0, 0);
    az1 = __builtin_amdgcn_mfma_f32_16x16x32_f16(at, bz1, az1, 0, 0, 0);

    const float g20 = g2v[n], g21 = g2v[16 + n];
    const float c20 = b2v[n], c21 = b2v[16 + n];
#pragma unroll
    for (int r = 0; r < 4; ++r) {
        const int pm = pbase + q * 4 + r;
        znext[pm * 16 + n] = __floats2half2_rn(relu_(fmaf(az0[r], g20, c20)),
                                               relu_(fmaf(az1[r], g21, c21)));
    }
}

}  // namespace

extern "C" void kernel_launch(void* const* d_in, const int* in_sizes, int n_in,
                              void* d_out, int out_size, void* d_ws, size_t ws_size,
                              hipStream_t stream)
{
    const float* x   = (const float*)d_in[0];
    const int4*  idx = (const int4*)d_in[1];
    const float* W2d = (const float*)d_in[2];
    const float* g2  = (const float*)d_in[3];
    const float* b2  = (const float*)d_in[4];
    const float* W1d = (const float*)d_in[5];
    const float* g1  = (const float*)d_in[6];
    const float* b1  = (const float*)d_in[7];
    float* out = (float*)d_out;     // doubles as sacc between dispatches
    char*  ws  = (char*)d_ws;

    constexpr size_t kHalfMap = (size_t)kPts * kD * sizeof(__half);  // 8 MB
    __half2* zA = (__half2*)(ws);
    __half2* zB = (__half2*)(ws + kHalfMap);
    uint4*   cA = (uint4*)(ws + 2 * kHalfMap);                 // x1 (fp16, pi order)
    uint4*   cB = (uint4*)(ws + 3 * kHalfMap);                 // x2 (fp16, pi order)
    uint2*   idx16 = (uint2*)(ws + 4 * kHalfMap);              // 4 MB
    uint4*   wpack = (uint4*)(ws + 4 * kHalfMap + (size_t)kPts * 32);  // 24 KB

    const dim3 grid(kBlocks), blk(kThreads);
    zprep_kernel<<<grid, blk, 0, stream>>>(x, idx, W2d, W1d, g2, b2,
                                           zA, idx16, wpack);

    const uint4* i16 = (const uint4*)idx16;
    blk_kernel<0><<<grid, blk, 0, stream>>>((const uint4*)zA, i16,
        wpack + (2 + 0 * 6) * 64, g1, b1, g2 + 1 * kD, b2 + 1 * kD,
        nullptr, cA, out, zB);
    blk_kernel<1><<<grid, blk, 0, stream>>>((const uint4*)zB, i16,
        wpack + (2 + 1 * 6) * 64, g1 + 1 * kD, b1 + 1 * kD, g2 + 2 * kD, b2 + 2 * kD,
        cA, cB, out, zA);
    blk_kernel<2><<<grid, blk, 0, stream>>>((const uint4*)zA, i16,
        wpack + (2 + 2 * 6) * 64, g1 + 2 * kD, b1 + 2 * kD, g2 + 3 * kD, b2 + 3 * kD,
        cB, nullptr, out, zB);
    blk_kernel<3><<<grid, blk, 0, stream>>>((const uint4*)zB, i16,
        wpack + (2 + 3 * 6) * 64, g1 + 3 * kD, b1 + 3 * kD, nullptr, nullptr,
        nullptr, nullptr, out, nullptr);
}